// Round 1
// baseline (421.571 us; speedup 1.0000x reference)
//
#include <hip/hip_runtime.h>
#include <hip/hip_bf16.h>

typedef __attribute__((ext_vector_type(8))) short bf16x8;
typedef __attribute__((ext_vector_type(4))) float f32x4;

__device__ __forceinline__ short to_bf16s(float f) {
    union { __hip_bfloat16 h; short s; } u;
    u.h = __float2bfloat16(f);
    return u.s;
}

__device__ __forceinline__ void load_lds16(const void* g, void* l) {
    __builtin_amdgcn_global_load_lds((const __attribute__((address_space(1))) void*)g,
                                     (__attribute__((address_space(3))) void*)l, 16, 0, 0);
}

// ---------------------------------------------------------------------------
// Weight transpose + fp32->bf16 cast:  W[K][N] fp32  ->  WT[N][K] bf16
// ---------------------------------------------------------------------------
__global__ __launch_bounds__(256)
void transpose_cast(const float* __restrict__ W, short* __restrict__ WT, int K, int N) {
    __shared__ float tile[32][33];
    const int k0 = blockIdx.y * 32, n0 = blockIdx.x * 32;
    const int t = threadIdx.x;
    {
        const int lr = t >> 3, lc = (t & 7) * 4;              // k-row, n-col
        float4 v = *(const float4*)&W[(long)(k0 + lr) * N + n0 + lc];
        tile[lr][lc] = v.x; tile[lr][lc + 1] = v.y;
        tile[lr][lc + 2] = v.z; tile[lr][lc + 3] = v.w;
    }
    __syncthreads();
    {
        const int nr = t >> 3, kc = (t & 7) * 4;              // n-row, k-col
        short4 o;
        o.x = to_bf16s(tile[kc][nr]);
        o.y = to_bf16s(tile[kc + 1][nr]);
        o.z = to_bf16s(tile[kc + 2][nr]);
        o.w = to_bf16s(tile[kc + 3][nr]);
        *(short4*)&WT[(long)(n0 + nr) * K + k0 + kc] = o;
    }
}

// ---------------------------------------------------------------------------
// RMSNorm (fp32 in) -> bf16 out.  One block per row, D=1024.
// ---------------------------------------------------------------------------
__global__ __launch_bounds__(256)
void rmsnorm_kernel(const float* __restrict__ x, const float* __restrict__ wt,
                    short* __restrict__ out) {
    const int D = 1024;
    const long row = blockIdx.x;
    const int t = threadIdx.x;
    float4 v = ((const float4*)(x + row * D))[t];
    float ss = v.x * v.x + v.y * v.y + v.z * v.z + v.w * v.w;
    #pragma unroll
    for (int off = 32; off; off >>= 1) ss += __shfl_xor(ss, off);
    __shared__ float red[4];
    if ((t & 63) == 0) red[t >> 6] = ss;
    __syncthreads();
    ss = red[0] + red[1] + red[2] + red[3];
    const float inv = rsqrtf(ss * (1.0f / 1024.0f) + 1e-6f);
    float4 wv = ((const float4*)wt)[t];
    short4 o;
    o.x = to_bf16s(v.x * inv * wv.x);
    o.y = to_bf16s(v.y * inv * wv.y);
    o.z = to_bf16s(v.z * inv * wv.z);
    o.w = to_bf16s(v.w * inv * wv.w);
    *(short4*)&out[row * D + t * 4] = o;
}

// ---------------------------------------------------------------------------
// 128x128-tile bf16 MFMA GEMM (m97 structure).  A[M][K] bf16, B[N][K] bf16.
// EPI 0: bf16 C[M][N]     1: bf16 C^T (out[N][M])
// EPI 2: fp32 out = res + C     3: bf16 out = silu(C0)*C1 (two B matrices)
// ---------------------------------------------------------------------------
template<int EPI>
__global__ __launch_bounds__(256)
void gemm128(const short* __restrict__ A, const short* __restrict__ B0,
             const short* __restrict__ B1, const float* __restrict__ res,
             void* __restrict__ outp, int M, int N, int K) {
    __shared__ short As[128 * 32];
    __shared__ short Bs[128 * 32];
    __shared__ short Bs1[(EPI == 3) ? 128 * 32 : 8];

    const int t = threadIdx.x;
    const int lane = t & 63, w = t >> 6;
    const int wr = w >> 1, wc = w & 1;
    const int bm = blockIdx.y, bn = blockIdx.x;

    const long arow = (long)(bm * 128 + (t >> 2)) * K + (t & 3) * 8;
    const long brow = (long)(bn * 128 + (t >> 2)) * K + (t & 3) * 8;

    f32x4 acc[4][4] = {};
    f32x4 acc2[4][4] = {};

    const int nk = K >> 5;
    for (int kt = 0; kt < nk; ++kt) {
        const int k0 = kt << 5;
        load_lds16(A + arow + k0,                 &As[t * 8]);
        load_lds16(A + arow + 64 * (long)K + k0,  &As[2048 + t * 8]);
        load_lds16(B0 + brow + k0,                &Bs[t * 8]);
        load_lds16(B0 + brow + 64 * (long)K + k0, &Bs[2048 + t * 8]);
        if constexpr (EPI == 3) {
            load_lds16(B1 + brow + k0,                &Bs1[t * 8]);
            load_lds16(B1 + brow + 64 * (long)K + k0, &Bs1[2048 + t * 8]);
        }
        __syncthreads();
        const int ko = (lane >> 4) * 8;
        bf16x8 a[4], b[4], b1[4];
        #pragma unroll
        for (int m = 0; m < 4; ++m)
            a[m] = *(const bf16x8*)&As[(wr * 64 + m * 16 + (lane & 15)) * 32 + ko];
        #pragma unroll
        for (int n = 0; n < 4; ++n)
            b[n] = *(const bf16x8*)&Bs[(wc * 64 + n * 16 + (lane & 15)) * 32 + ko];
        if constexpr (EPI == 3) {
            #pragma unroll
            for (int n = 0; n < 4; ++n)
                b1[n] = *(const bf16x8*)&Bs1[(wc * 64 + n * 16 + (lane & 15)) * 32 + ko];
        }
        #pragma unroll
        for (int m = 0; m < 4; ++m)
            #pragma unroll
            for (int n = 0; n < 4; ++n) {
                acc[m][n] = __builtin_amdgcn_mfma_f32_16x16x32_bf16(a[m], b[n], acc[m][n], 0, 0, 0);
                if constexpr (EPI == 3)
                    acc2[m][n] = __builtin_amdgcn_mfma_f32_16x16x32_bf16(a[m], b1[n], acc2[m][n], 0, 0, 0);
            }
        __syncthreads();
    }

    #pragma unroll
    for (int m = 0; m < 4; ++m)
      #pragma unroll
      for (int n = 0; n < 4; ++n)
        #pragma unroll
        for (int r = 0; r < 4; ++r) {
            const int grow = bm * 128 + wr * 64 + m * 16 + ((lane >> 4) << 2) + r;
            const int gcol = bn * 128 + wc * 64 + n * 16 + (lane & 15);
            const float v = acc[m][n][r];
            if constexpr (EPI == 0) {
                ((short*)outp)[(long)grow * N + gcol] = to_bf16s(v);
            } else if constexpr (EPI == 1) {
                ((short*)outp)[(long)gcol * M + grow] = to_bf16s(v);
            } else if constexpr (EPI == 2) {
                const long i = (long)grow * N + gcol;
                ((float*)outp)[i] = res[i] + v;
            } else {
                const float g = v;
                const float sw = g / (1.f + __expf(-g));
                ((short*)outp)[(long)grow * N + gcol] = to_bf16s(sw * acc2[m][n][r]);
            }
        }
}

// ---------------------------------------------------------------------------
// Windowed causal attention (WINDOW=64, D=1024).  32 queries / block,
// 96-key span.  Q,K bf16 [8192][1024]; VT bf16 [1024][8192]; att bf16 out.
// ---------------------------------------------------------------------------
__global__ __launch_bounds__(128)
void attn_kernel(const short* __restrict__ Q, const short* __restrict__ Km,
                 const short* __restrict__ VT, short* __restrict__ att) {
    const int T = 2048, D = 1024, Mtot = 8192;
    const int bid = blockIdx.x;
    const int b = bid >> 6;                 // batch
    const int q0 = (bid & 63) << 5;         // local query tile start
    const long qrow0 = (long)b * T + q0;
    const int t = threadIdx.x, lane = t & 63, w = t >> 6;

    __shared__ short Qs[32 * 32];
    __shared__ short Ks[96 * 32];
    __shared__ float S_lds[32][100];
    __shared__ short P_lds[32 * 96];
    __shared__ short VTs[128 * 96];

    // ---- S = Q K^T over K=1024 ----
    f32x4 s[6] = {};
    const int trow = t >> 2, tk8 = (t & 3) * 8;
    for (int kt = 0; kt < 32; ++kt) {
        const int k0 = kt << 5;
        load_lds16(Q + (qrow0 + trow) * D + k0 + tk8, &Qs[t * 8]);
        #pragma unroll
        for (int s2 = 0; s2 < 3; ++s2) {
            const int krow = s2 * 32 + trow;
            int j = q0 - 64 + krow; if (j < 0) j = 0;        // clamped; masked later
            load_lds16(Km + ((long)b * T + j) * D + k0 + tk8, &Ks[(s2 * 128 + t) * 8]);
        }
        __syncthreads();
        const int ko = (lane >> 4) * 8;
        const bf16x8 aq = *(const bf16x8*)&Qs[(w * 16 + (lane & 15)) * 32 + ko];
        #pragma unroll
        for (int n = 0; n < 6; ++n) {
            const bf16x8 bk = *(const bf16x8*)&Ks[(n * 16 + (lane & 15)) * 32 + ko];
            s[n] = __builtin_amdgcn_mfma_f32_16x16x32_bf16(aq, bk, s[n], 0, 0, 0);
        }
        __syncthreads();
    }
    #pragma unroll
    for (int n = 0; n < 6; ++n)
        #pragma unroll
        for (int r = 0; r < 4; ++r)
            S_lds[w * 16 + ((lane >> 4) << 2) + r][n * 16 + (lane & 15)] = s[n][r] * 0.03125f;
    __syncthreads();

    // ---- masked softmax: row qi attends kj in (qi, qi+64], j_local>=0 ----
    {
        const int row = t >> 2, c0 = (t & 3) * 24;
        float e[24];
        float mx = -1e30f;
        #pragma unroll
        for (int c = 0; c < 24; ++c) {
            const int kj = c0 + c;
            const bool valid = (kj > row) && (kj <= row + 64) && (q0 - 64 + kj >= 0);
            const float sv = valid ? S_lds[row][kj] : -1e30f;
            e[c] = sv;
            mx = fmaxf(mx, sv);
        }
        mx = fmaxf(mx, __shfl_xor(mx, 1));
        mx = fmaxf(mx, __shfl_xor(mx, 2));
        float sum = 0.f;
        #pragma unroll
        for (int c = 0; c < 24; ++c) {
            const float ev = (e[c] > -1e29f) ? __expf(e[c] - mx) : 0.f;
            e[c] = ev; sum += ev;
        }
        sum += __shfl_xor(sum, 1);
        sum += __shfl_xor(sum, 2);
        const float inv = 1.f / sum;
        #pragma unroll
        for (int c = 0; c < 24; ++c)
            P_lds[row * 96 + c0 + c] = to_bf16s(e[c] * inv);
    }
    __syncthreads();

    // ---- attended = P V  (Vt staged per 128-d chunk, linear LDS) ----
    bf16x8 pa[3];
    {
        const int ko = (lane >> 4) * 8;
        #pragma unroll
        for (int kc = 0; kc < 3; ++kc)
            pa[kc] = *(const bf16x8*)&P_lds[(w * 16 + (lane & 15)) * 96 + kc * 32 + ko];
    }
    for (int dc = 0; dc < 8; ++dc) {
        #pragma unroll
        for (int s2 = 0; s2 < 12; ++s2) {
            const int idx = s2 * 128 + t;
            const int dr = idx / 12, c = idx - dr * 12;
            int j = q0 - 64 + c * 8; if (j < 0) j = 0;       // chunk-aligned clamp
            load_lds16(VT + (long)(dc * 128 + dr) * Mtot + b * T + j, &VTs[idx * 8]);
        }
        __syncthreads();
        f32x4 o[8] = {};
        const int ko = (lane >> 4) * 8;
        #pragma unroll
        for (int kc = 0; kc < 3; ++kc)
            #pragma unroll
            for (int n = 0; n < 8; ++n) {
                const bf16x8 vb = *(const bf16x8*)&VTs[(n * 16 + (lane & 15)) * 96 + kc * 32 + ko];
                o[n] = __builtin_amdgcn_mfma_f32_16x16x32_bf16(pa[kc], vb, o[n], 0, 0, 0);
            }
        __syncthreads();
        #pragma unroll
        for (int n = 0; n < 8; ++n)
            #pragma unroll
            for (int r = 0; r < 4; ++r) {
                const long grow = qrow0 + w * 16 + ((lane >> 4) << 2) + r;
                const int gcol = dc * 128 + n * 16 + (lane & 15);
                att[grow * D + gcol] = to_bf16s(o[n][r]);
            }
    }
}

// ---------------------------------------------------------------------------
extern "C" void kernel_launch(void* const* d_in, const int* in_sizes, int n_in,
                              void* d_out, int out_size, void* d_ws, size_t ws_size,
                              hipStream_t stream) {
    const float* x   = (const float*)d_in[0];
    const float* n1w = (const float*)d_in[1];
    const float* n2w = (const float*)d_in[2];
    const float* Wq  = (const float*)d_in[3];
    const float* Wk  = (const float*)d_in[4];
    const float* Wv  = (const float*)d_in[5];
    const float* Wo  = (const float*)d_in[6];
    const float* W1  = (const float*)d_in[7];
    const float* W2  = (const float*)d_in[8];
    const float* W3  = (const float*)d_in[9];

    const int M = 8192;           // B*T
    char* ws = (char*)d_ws;
    size_t off = 0;
    auto alloc = [&](size_t bytes) { void* p = ws + off; off += (bytes + 255) & ~(size_t)255; return p; };

    short* xn1 = (short*)alloc((size_t)M * 1024 * 2);   // reused as att
    short* qb  = (short*)alloc((size_t)M * 1024 * 2);   // reused as xn2
    short* kb  = (short*)alloc((size_t)M * 1024 * 2);   // reused as h (with vT)
    short* vT  = (short*)alloc((size_t)M * 1024 * 2);
    float* x2  = (float*)alloc((size_t)M * 1024 * 4);
    short* WqT = (short*)alloc((size_t)1024 * 1024 * 2);
    short* WkT = (short*)alloc((size_t)1024 * 1024 * 2);
    short* WvT = (short*)alloc((size_t)1024 * 1024 * 2);
    short* WoT = (short*)alloc((size_t)1024 * 1024 * 2);
    short* W1T = (short*)alloc((size_t)2048 * 1024 * 2);
    short* W3T = (short*)alloc((size_t)2048 * 1024 * 2);
    short* W2T = (short*)alloc((size_t)1024 * 2048 * 2);
    short* att = xn1;             // alias: xn1 dead after QKV GEMMs
    short* xn2 = qb;              // alias: q dead after attention
    short* h   = kb;              // alias: k,vT dead after attention (33.5MB spans both)

    // Weight transposes (fp32 -> bf16 [N][K])
    transpose_cast<<<dim3(32, 32), 256, 0, stream>>>(Wq, WqT, 1024, 1024);
    transpose_cast<<<dim3(32, 32), 256, 0, stream>>>(Wk, WkT, 1024, 1024);
    transpose_cast<<<dim3(32, 32), 256, 0, stream>>>(Wv, WvT, 1024, 1024);
    transpose_cast<<<dim3(32, 32), 256, 0, stream>>>(Wo, WoT, 1024, 1024);
    transpose_cast<<<dim3(64, 32), 256, 0, stream>>>(W1, W1T, 1024, 2048);
    transpose_cast<<<dim3(64, 32), 256, 0, stream>>>(W3, W3T, 1024, 2048);
    transpose_cast<<<dim3(32, 64), 256, 0, stream>>>(W2, W2T, 2048, 1024);

    // norm1 -> xn1 (bf16)
    rmsnorm_kernel<<<M, 256, 0, stream>>>(x, n1w, xn1);
    // QKV
    gemm128<0><<<dim3(8, 64), 256, 0, stream>>>(xn1, WqT, nullptr, nullptr, qb, M, 1024, 1024);
    gemm128<0><<<dim3(8, 64), 256, 0, stream>>>(xn1, WkT, nullptr, nullptr, kb, M, 1024, 1024);
    gemm128<1><<<dim3(8, 64), 256, 0, stream>>>(xn1, WvT, nullptr, nullptr, vT, M, 1024, 1024);
    // attention -> att (bf16)  [att aliases xn1]
    attn_kernel<<<256, 128, 0, stream>>>(qb, kb, vT, att);
    // x2 = x + att @ Wo   (fp32)
    gemm128<2><<<dim3(8, 64), 256, 0, stream>>>(att, WoT, nullptr, x, x2, M, 1024, 1024);
    // norm2 -> xn2 (bf16)
    rmsnorm_kernel<<<M, 256, 0, stream>>>(x2, n2w, xn2);
    // h = silu(xn2@W1) * (xn2@W3)   (bf16)
    gemm128<3><<<dim3(16, 64), 256, 0, stream>>>(xn2, W1T, W3T, nullptr, h, M, 2048, 1024);
    // out = x2 + h @ W2   (fp32)
    gemm128<2><<<dim3(8, 64), 256, 0, stream>>>(h, W2T, nullptr, x2, (float*)d_out, M, 1024, 2048);
}

// Round 2
// 346.629 us; speedup vs baseline: 1.2162x; 1.2162x over previous
//
#include <hip/hip_runtime.h>
#include <hip/hip_bf16.h>

typedef __attribute__((ext_vector_type(8))) short bf16x8;
typedef __attribute__((ext_vector_type(4))) float f32x4;

__device__ __forceinline__ short to_bf16s(float f) {
    union { __hip_bfloat16 h; short s; } u;
    u.h = __float2bfloat16(f);
    return u.s;
}

__device__ __forceinline__ float bf16s_to_f(short s) {
    union { float f; unsigned u; } cv;
    cv.u = ((unsigned)(unsigned short)s) << 16;
    return cv.f;
}

__device__ __forceinline__ void load_lds16(const void* g, void* l) {
    __builtin_amdgcn_global_load_lds((const __attribute__((address_space(1))) void*)g,
                                     (__attribute__((address_space(3))) void*)l, 16, 0, 0);
}

// ---------------------------------------------------------------------------
// All 7 weight transposes (fp32 [K][N] -> bf16 [N][K]) in one launch.
// ---------------------------------------------------------------------------
__global__ __launch_bounds__(256)
void transpose_all(const float* __restrict__ Wq, const float* __restrict__ Wk,
                   const float* __restrict__ Wv, const float* __restrict__ Wo,
                   const float* __restrict__ W1, const float* __restrict__ W3,
                   const float* __restrict__ W2,
                   short* __restrict__ WqT, short* __restrict__ WkT,
                   short* __restrict__ WvT, short* __restrict__ WoT,
                   short* __restrict__ W1T, short* __restrict__ W3T,
                   short* __restrict__ W2T) {
    __shared__ float tile[32][33];
    const int bid = blockIdx.x;
    const float* src; short* dst; int K, N, tl;
    if (bid < 4096) {
        const int wi = bid >> 10; tl = bid & 1023;
        src = wi == 0 ? Wq : wi == 1 ? Wk : wi == 2 ? Wv : Wo;
        dst = wi == 0 ? WqT : wi == 1 ? WkT : wi == 2 ? WvT : WoT;
        K = 1024; N = 1024;
    } else if (bid < 8192) {
        const int wi = (bid - 4096) >> 11; tl = (bid - 4096) & 2047;
        src = wi ? W3 : W1; dst = wi ? W3T : W1T;
        K = 1024; N = 2048;
    } else {
        tl = bid - 8192; src = W2; dst = W2T;
        K = 2048; N = 1024;
    }
    const int nx = N >> 5;
    const int n0 = (tl % nx) * 32, k0 = (tl / nx) * 32;
    const int t = threadIdx.x;
    {
        const int lr = t >> 3, lc = (t & 7) * 4;              // k-row, n-col
        float4 v = *(const float4*)&src[(long)(k0 + lr) * N + n0 + lc];
        tile[lr][lc] = v.x; tile[lr][lc + 1] = v.y;
        tile[lr][lc + 2] = v.z; tile[lr][lc + 3] = v.w;
    }
    __syncthreads();
    {
        const int nr = t >> 3, kc = (t & 7) * 4;              // n-row, k-col
        short4 o;
        o.x = to_bf16s(tile[kc][nr]);
        o.y = to_bf16s(tile[kc + 1][nr]);
        o.z = to_bf16s(tile[kc + 2][nr]);
        o.w = to_bf16s(tile[kc + 3][nr]);
        *(short4*)&dst[(long)(n0 + nr) * K + k0 + kc] = o;
    }
}

// ---------------------------------------------------------------------------
// RMSNorm (fp32 in) -> bf16 out.  One block per row, D=1024.
// ---------------------------------------------------------------------------
__global__ __launch_bounds__(256)
void rmsnorm_kernel(const float* __restrict__ x, const float* __restrict__ wt,
                    short* __restrict__ out) {
    const int D = 1024;
    const long row = blockIdx.x;
    const int t = threadIdx.x;
    float4 v = ((const float4*)(x + row * D))[t];
    float ss = v.x * v.x + v.y * v.y + v.z * v.z + v.w * v.w;
    #pragma unroll
    for (int off = 32; off; off >>= 1) ss += __shfl_xor(ss, off);
    __shared__ float red[4];
    if ((t & 63) == 0) red[t >> 6] = ss;
    __syncthreads();
    ss = red[0] + red[1] + red[2] + red[3];
    const float inv = rsqrtf(ss * (1.0f / 1024.0f) + 1e-6f);
    float4 wv = ((const float4*)wt)[t];
    short4 o;
    o.x = to_bf16s(v.x * inv * wv.x);
    o.y = to_bf16s(v.y * inv * wv.y);
    o.z = to_bf16s(v.z * inv * wv.z);
    o.w = to_bf16s(v.w * inv * wv.w);
    *(short4*)&out[row * D + t * 4] = o;
}

// ---------------------------------------------------------------------------
// 128x128-tile bf16 MFMA GEMM, 2-phase double-buffered (T3-minimal).
// A[M][K] bf16, B[N][K] bf16.
// EPI 0: bf16 C[M][N]            1: bf16 C^T (out[N][M])
// EPI 2: fp32 out = res + C      4: bf16 out = silu(aux)*C (in-place over aux)
// ---------------------------------------------------------------------------
template<int EPI>
__global__ __launch_bounds__(256)
void gemm128(const short* __restrict__ A, const short* __restrict__ B0,
             const short* __restrict__ aux, const float* __restrict__ res,
             void* __restrict__ outp, int M, int N, int K) {
    __shared__ short As[2][128 * 32];
    __shared__ short Bs[2][128 * 32];

    const int t = threadIdx.x;
    const int lane = t & 63, w = t >> 6;
    const int wr = w >> 1, wc = w & 1;
    const int bm = blockIdx.y, bn = blockIdx.x;

    const long arow = (long)(bm * 128 + (t >> 2)) * K + (t & 3) * 8;
    const long brow = (long)(bn * 128 + (t >> 2)) * K + (t & 3) * 8;

    f32x4 acc[4][4] = {};
    const int nk = K >> 5;

    auto stage = [&](int buf, int kt) {
        const int k0 = kt << 5;
        load_lds16(A + arow + k0,                 &As[buf][t * 8]);
        load_lds16(A + arow + 64 * (long)K + k0,  &As[buf][2048 + t * 8]);
        load_lds16(B0 + brow + k0,                &Bs[buf][t * 8]);
        load_lds16(B0 + brow + 64 * (long)K + k0, &Bs[buf][2048 + t * 8]);
    };

    stage(0, 0);
    __syncthreads();
    int cur = 0;
    for (int kt = 0; kt < nk; ++kt) {
        if (kt + 1 < nk) stage(cur ^ 1, kt + 1);   // prefetch next tile (overlaps MFMA)
        const int ko = (lane >> 4) * 8;
        bf16x8 a[4], b[4];
        #pragma unroll
        for (int m = 0; m < 4; ++m)
            a[m] = *(const bf16x8*)&As[cur][(wr * 64 + m * 16 + (lane & 15)) * 32 + ko];
        #pragma unroll
        for (int n = 0; n < 4; ++n)
            b[n] = *(const bf16x8*)&Bs[cur][(wc * 64 + n * 16 + (lane & 15)) * 32 + ko];
        #pragma unroll
        for (int m = 0; m < 4; ++m)
            #pragma unroll
            for (int n = 0; n < 4; ++n)
                acc[m][n] = __builtin_amdgcn_mfma_f32_16x16x32_bf16(a[m], b[n], acc[m][n], 0, 0, 0);
        __syncthreads();                           // one drain+barrier per K-step
        cur ^= 1;
    }

    #pragma unroll
    for (int m = 0; m < 4; ++m)
      #pragma unroll
      for (int n = 0; n < 4; ++n)
        #pragma unroll
        for (int r = 0; r < 4; ++r) {
            const int grow = bm * 128 + wr * 64 + m * 16 + ((lane >> 4) << 2) + r;
            const int gcol = bn * 128 + wc * 64 + n * 16 + (lane & 15);
            const float v = acc[m][n][r];
            if constexpr (EPI == 0) {
                ((short*)outp)[(long)grow * N + gcol] = to_bf16s(v);
            } else if constexpr (EPI == 1) {
                ((short*)outp)[(long)gcol * M + grow] = to_bf16s(v);
            } else if constexpr (EPI == 2) {
                const long i = (long)grow * N + gcol;
                ((float*)outp)[i] = res[i] + v;
            } else {
                const long i = (long)grow * N + gcol;
                const float g = bf16s_to_f(aux[i]);
                const float sw = g / (1.f + __expf(-g));
                ((short*)outp)[i] = to_bf16s(sw * v);
            }
        }
}

// ---------------------------------------------------------------------------
// Windowed causal attention (WINDOW=64, D=1024).  32 queries / block,
// 96-key span.  Q,K bf16 [8192][1024]; VT bf16 [1024][8192]; att bf16 out.
// ---------------------------------------------------------------------------
__global__ __launch_bounds__(128)
void attn_kernel(const short* __restrict__ Q, const short* __restrict__ Km,
                 const short* __restrict__ VT, short* __restrict__ att) {
    const int T = 2048, D = 1024, Mtot = 8192;
    const int bid = blockIdx.x;
    const int b = bid >> 6;                 // batch
    const int q0 = (bid & 63) << 5;         // local query tile start
    const long qrow0 = (long)b * T + q0;
    const int t = threadIdx.x, lane = t & 63, w = t >> 6;

    __shared__ short Qs[32 * 32];
    __shared__ short Ks[96 * 32];
    __shared__ float S_lds[32][100];
    __shared__ short P_lds[32 * 96];
    __shared__ short VTs[128 * 96];

    // ---- S = Q K^T over K=1024 ----
    f32x4 s[6] = {};
    const int trow = t >> 2, tk8 = (t & 3) * 8;
    for (int kt = 0; kt < 32; ++kt) {
        const int k0 = kt << 5;
        load_lds16(Q + (qrow0 + trow) * D + k0 + tk8, &Qs[t * 8]);
        #pragma unroll
        for (int s2 = 0; s2 < 3; ++s2) {
            const int krow = s2 * 32 + trow;
            int j = q0 - 64 + krow; if (j < 0) j = 0;        // clamped; masked later
            load_lds16(Km + ((long)b * T + j) * D + k0 + tk8, &Ks[(s2 * 128 + t) * 8]);
        }
        __syncthreads();
        const int ko = (lane >> 4) * 8;
        const bf16x8 aq = *(const bf16x8*)&Qs[(w * 16 + (lane & 15)) * 32 + ko];
        #pragma unroll
        for (int n = 0; n < 6; ++n) {
            const bf16x8 bk = *(const bf16x8*)&Ks[(n * 16 + (lane & 15)) * 32 + ko];
            s[n] = __builtin_amdgcn_mfma_f32_16x16x32_bf16(aq, bk, s[n], 0, 0, 0);
        }
        __syncthreads();
    }
    #pragma unroll
    for (int n = 0; n < 6; ++n)
        #pragma unroll
        for (int r = 0; r < 4; ++r)
            S_lds[w * 16 + ((lane >> 4) << 2) + r][n * 16 + (lane & 15)] = s[n][r] * 0.03125f;
    __syncthreads();

    // ---- masked softmax: row qi attends kj in (qi, qi+64], j_local>=0 ----
    {
        const int row = t >> 2, c0 = (t & 3) * 24;
        float e[24];
        float mx = -1e30f;
        #pragma unroll
        for (int c = 0; c < 24; ++c) {
            const int kj = c0 + c;
            const bool valid = (kj > row) && (kj <= row + 64) && (q0 - 64 + kj >= 0);
            const float sv = valid ? S_lds[row][kj] : -1e30f;
            e[c] = sv;
            mx = fmaxf(mx, sv);
        }
        mx = fmaxf(mx, __shfl_xor(mx, 1));
        mx = fmaxf(mx, __shfl_xor(mx, 2));
        float sum = 0.f;
        #pragma unroll
        for (int c = 0; c < 24; ++c) {
            const float ev = (e[c] > -1e29f) ? __expf(e[c] - mx) : 0.f;
            e[c] = ev; sum += ev;
        }
        sum += __shfl_xor(sum, 1);
        sum += __shfl_xor(sum, 2);
        const float inv = 1.f / sum;
        #pragma unroll
        for (int c = 0; c < 24; ++c)
            P_lds[row * 96 + c0 + c] = to_bf16s(e[c] * inv);
    }
    __syncthreads();

    // ---- attended = P V  (Vt staged per 128-d chunk, linear LDS) ----
    bf16x8 pa[3];
    {
        const int ko = (lane >> 4) * 8;
        #pragma unroll
        for (int kc = 0; kc < 3; ++kc)
            pa[kc] = *(const bf16x8*)&P_lds[(w * 16 + (lane & 15)) * 96 + kc * 32 + ko];
    }
    for (int dc = 0; dc < 8; ++dc) {
        #pragma unroll
        for (int s2 = 0; s2 < 12; ++s2) {
            const int idx = s2 * 128 + t;
            const int dr = idx / 12, c = idx - dr * 12;
            int j = q0 - 64 + c * 8; if (j < 0) j = 0;       // chunk-aligned clamp
            load_lds16(VT + (long)(dc * 128 + dr) * Mtot + b * T + j, &VTs[idx * 8]);
        }
        __syncthreads();
        f32x4 o[8] = {};
        const int ko = (lane >> 4) * 8;
        #pragma unroll
        for (int kc = 0; kc < 3; ++kc)
            #pragma unroll
            for (int n = 0; n < 8; ++n) {
                const bf16x8 vb = *(const bf16x8*)&VTs[(n * 16 + (lane & 15)) * 96 + kc * 32 + ko];
                o[n] = __builtin_amdgcn_mfma_f32_16x16x32_bf16(pa[kc], vb, o[n], 0, 0, 0);
            }
        __syncthreads();
        #pragma unroll
        for (int n = 0; n < 8; ++n)
            #pragma unroll
            for (int r = 0; r < 4; ++r) {
                const long grow = qrow0 + w * 16 + ((lane >> 4) << 2) + r;
                const int gcol = dc * 128 + n * 16 + (lane & 15);
                att[grow * D + gcol] = to_bf16s(o[n][r]);
            }
    }
}

// ---------------------------------------------------------------------------
extern "C" void kernel_launch(void* const* d_in, const int* in_sizes, int n_in,
                              void* d_out, int out_size, void* d_ws, size_t ws_size,
                              hipStream_t stream) {
    const float* x   = (const float*)d_in[0];
    const float* n1w = (const float*)d_in[1];
    const float* n2w = (const float*)d_in[2];
    const float* Wq  = (const float*)d_in[3];
    const float* Wk  = (const float*)d_in[4];
    const float* Wv  = (const float*)d_in[5];
    const float* Wo  = (const float*)d_in[6];
    const float* W1  = (const float*)d_in[7];
    const float* W2  = (const float*)d_in[8];
    const float* W3  = (const float*)d_in[9];

    const int M = 8192;           // B*T
    char* ws = (char*)d_ws;
    size_t off = 0;
    auto alloc = [&](size_t bytes) { void* p = ws + off; off += (bytes + 255) & ~(size_t)255; return p; };

    short* xn1 = (short*)alloc((size_t)M * 1024 * 2);   // reused as att
    short* qb  = (short*)alloc((size_t)M * 1024 * 2);   // reused as xn2
    short* kb  = (short*)alloc((size_t)M * 1024 * 2);   // reused as g1/h (spans kb+vT)
    short* vT  = (short*)alloc((size_t)M * 1024 * 2);
    float* x2  = (float*)alloc((size_t)M * 1024 * 4);
    short* WqT = (short*)alloc((size_t)1024 * 1024 * 2);
    short* WkT = (short*)alloc((size_t)1024 * 1024 * 2);
    short* WvT = (short*)alloc((size_t)1024 * 1024 * 2);
    short* WoT = (short*)alloc((size_t)1024 * 1024 * 2);
    short* W1T = (short*)alloc((size_t)2048 * 1024 * 2);
    short* W3T = (short*)alloc((size_t)2048 * 1024 * 2);
    short* W2T = (short*)alloc((size_t)1024 * 2048 * 2);
    short* att = xn1;             // alias: xn1 dead after QKV GEMMs
    short* xn2 = qb;              // alias: q dead after attention
    short* g1  = kb;              // alias: k,vT dead after attention (33.5MB spans both)

    // All weight transposes (fp32 -> bf16 [N][K]) in one launch
    transpose_all<<<10240, 256, 0, stream>>>(Wq, Wk, Wv, Wo, W1, W3, W2,
                                             WqT, WkT, WvT, WoT, W1T, W3T, W2T);

    // norm1 -> xn1 (bf16)
    rmsnorm_kernel<<<M, 256, 0, stream>>>(x, n1w, xn1);
    // QKV
    gemm128<0><<<dim3(8, 64), 256, 0, stream>>>(xn1, WqT, nullptr, nullptr, qb, M, 1024, 1024);
    gemm128<0><<<dim3(8, 64), 256, 0, stream>>>(xn1, WkT, nullptr, nullptr, kb, M, 1024, 1024);
    gemm128<1><<<dim3(8, 64), 256, 0, stream>>>(xn1, WvT, nullptr, nullptr, vT, M, 1024, 1024);
    // attention -> att (bf16)  [att aliases xn1]
    attn_kernel<<<256, 128, 0, stream>>>(qb, kb, vT, att);
    // x2 = x + att @ Wo   (fp32)
    gemm128<2><<<dim3(8, 64), 256, 0, stream>>>(att, WoT, nullptr, x, x2, M, 1024, 1024);
    // norm2 -> xn2 (bf16)
    rmsnorm_kernel<<<M, 256, 0, stream>>>(x2, n2w, xn2);
    // g1 = xn2 @ W1   (bf16)  [g1 over dead kb+vT]
    gemm128<0><<<dim3(16, 64), 256, 0, stream>>>(xn2, W1T, nullptr, nullptr, g1, M, 2048, 1024);
    // h = silu(g1) * (xn2 @ W3)   (bf16, in-place over g1)
    gemm128<4><<<dim3(16, 64), 256, 0, stream>>>(xn2, W3T, g1, nullptr, g1, M, 2048, 1024);
    // out = x2 + h @ W2   (fp32)
    gemm128<2><<<dim3(8, 64), 256, 0, stream>>>(g1, W2T, nullptr, x2, (float*)d_out, M, 1024, 2048);
}

// Round 3
// 327.897 us; speedup vs baseline: 1.2857x; 1.0571x over previous
//
#include <hip/hip_runtime.h>
#include <hip/hip_bf16.h>

typedef __attribute__((ext_vector_type(8))) short bf16x8;
typedef __attribute__((ext_vector_type(4))) float f32x4;

__device__ __forceinline__ short to_bf16s(float f) {
    union { __hip_bfloat16 h; short s; } u;
    u.h = __float2bfloat16(f);
    return u.s;
}

__device__ __forceinline__ float bf16s_to_f(short s) {
    union { float f; unsigned u; } cv;
    cv.u = ((unsigned)(unsigned short)s) << 16;
    return cv.f;
}

__device__ __forceinline__ void load_lds16(const void* g, void* l) {
    __builtin_amdgcn_global_load_lds((const __attribute__((address_space(1))) void*)g,
                                     (__attribute__((address_space(3))) void*)l, 16, 0, 0);
}

// ---------------------------------------------------------------------------
// All 7 weight transposes (fp32 [K][N] -> bf16 [N][K]) in one launch.
// ---------------------------------------------------------------------------
__global__ __launch_bounds__(256)
void transpose_all(const float* __restrict__ Wq, const float* __restrict__ Wk,
                   const float* __restrict__ Wv, const float* __restrict__ Wo,
                   const float* __restrict__ W1, const float* __restrict__ W3,
                   const float* __restrict__ W2,
                   short* __restrict__ WqT, short* __restrict__ WkT,
                   short* __restrict__ WvT, short* __restrict__ WoT,
                   short* __restrict__ W1T, short* __restrict__ W3T,
                   short* __restrict__ W2T) {
    __shared__ float tile[32][33];
    const int bid = blockIdx.x;
    const float* src; short* dst; int K, N, tl;
    if (bid < 4096) {
        const int wi = bid >> 10; tl = bid & 1023;
        src = wi == 0 ? Wq : wi == 1 ? Wk : wi == 2 ? Wv : Wo;
        dst = wi == 0 ? WqT : wi == 1 ? WkT : wi == 2 ? WvT : WoT;
        K = 1024; N = 1024;
    } else if (bid < 8192) {
        const int wi = (bid - 4096) >> 11; tl = (bid - 4096) & 2047;
        src = wi ? W3 : W1; dst = wi ? W3T : W1T;
        K = 1024; N = 2048;
    } else {
        tl = bid - 8192; src = W2; dst = W2T;
        K = 2048; N = 1024;
    }
    const int nx = N >> 5;
    const int n0 = (tl % nx) * 32, k0 = (tl / nx) * 32;
    const int t = threadIdx.x;
    {
        const int lr = t >> 3, lc = (t & 7) * 4;
        float4 v = *(const float4*)&src[(long)(k0 + lr) * N + n0 + lc];
        tile[lr][lc] = v.x; tile[lr][lc + 1] = v.y;
        tile[lr][lc + 2] = v.z; tile[lr][lc + 3] = v.w;
    }
    __syncthreads();
    {
        const int nr = t >> 3, kc = (t & 7) * 4;
        short4 o;
        o.x = to_bf16s(tile[kc][nr]);
        o.y = to_bf16s(tile[kc + 1][nr]);
        o.z = to_bf16s(tile[kc + 2][nr]);
        o.w = to_bf16s(tile[kc + 3][nr]);
        *(short4*)&dst[(long)(n0 + nr) * K + k0 + kc] = o;
    }
}

// ---------------------------------------------------------------------------
// RMSNorm (fp32 in) -> bf16 out.  One block per row, D=1024.
// ---------------------------------------------------------------------------
__global__ __launch_bounds__(256)
void rmsnorm_kernel(const float* __restrict__ x, const float* __restrict__ wt,
                    short* __restrict__ out) {
    const int D = 1024;
    const long row = blockIdx.x;
    const int t = threadIdx.x;
    float4 v = ((const float4*)(x + row * D))[t];
    float ss = v.x * v.x + v.y * v.y + v.z * v.z + v.w * v.w;
    #pragma unroll
    for (int off = 32; off; off >>= 1) ss += __shfl_xor(ss, off);
    __shared__ float red[4];
    if ((t & 63) == 0) red[t >> 6] = ss;
    __syncthreads();
    ss = red[0] + red[1] + red[2] + red[3];
    const float inv = rsqrtf(ss * (1.0f / 1024.0f) + 1e-6f);
    float4 wv = ((const float4*)wt)[t];
    short4 o;
    o.x = to_bf16s(v.x * inv * wv.x);
    o.y = to_bf16s(v.y * inv * wv.y);
    o.z = to_bf16s(v.z * inv * wv.z);
    o.w = to_bf16s(v.w * inv * wv.w);
    *(short4*)&out[row * D + t * 4] = o;
}

// ---------------------------------------------------------------------------
// 8-phase-style counted-vmcnt bf16 MFMA GEMM.
// BM=128, BN=256, BK=64, 512 threads = 8 waves (2 wr x 4 wc), per-wave C 64x64.
// 3-deep LDS ring (48 KiB/buf = A 16K + B 32K), T2 XOR-swizzle via
// inverse-swizzled global source (linear LDS dest, rule #21).
// vmcnt(6) at each K-tile boundary (2 tiles in flight), raw s_barrier,
// lgkmcnt(0)+sched_barrier before MFMA, setprio(1) around MFMA clusters.
// A[M][K] bf16, B[N][K] bf16.
// EPI 0: bf16 C[M][N]
// EPI 2: fp32 out = res + C
// EPI 4: bf16 out = silu(aux)*C (in-place over aux)
// EPI 5: QKV split: cols<2048 -> bf16 outp[row][2048];  cols>=2048 ->
//        transposed bf16 outp2[col-2048][8192]
// ---------------------------------------------------------------------------
template<int EPI>
__global__ __launch_bounds__(512, 2)
void gemm8p(const short* __restrict__ A, const short* __restrict__ B0,
            const short* __restrict__ aux, const float* __restrict__ res,
            void* __restrict__ outp, short* __restrict__ outp2,
            int M, int N, int K) {
    __shared__ __align__(16) char lds[3][49152];   // [buf][A 0..16384 | B 16384..49152]

    const int t = threadIdx.x;
    const int lane = t & 63, w = t >> 6;
    const int wr = w >> 2, wc = w & 3;             // 2 x 4 wave grid
    const int bm = blockIdx.y, bn = blockIdx.x;
    const long Kb = (long)K * 2;                   // row stride in bytes

    // ---- staging source byte-offsets (inverse-swizzled global addresses) ----
    const char* Ab = (const char*)A;
    const char* Bb = (const char*)B0;
    long asrc[2], bsrc[4];
    #pragma unroll
    for (int i = 0; i < 2; ++i) {
        const int X = i * 8192 + t * 16;           // linear LDS byte pos
        const int row = X >> 7, cb = X & 127;
        asrc[i] = (long)(bm * 128 + row) * Kb + (cb ^ ((row & 7) << 4));
    }
    #pragma unroll
    for (int j = 0; j < 4; ++j) {
        const int X = j * 8192 + t * 16;
        const int row = X >> 7, cb = X & 127;
        bsrc[j] = (long)(bn * 256 + row) * Kb + (cb ^ ((row & 7) << 4));
    }

    auto stageA = [&](int buf, int kt) {
        load_lds16(Ab + asrc[0] + kt * 128, &lds[buf][t * 16]);
        load_lds16(Ab + asrc[1] + kt * 128, &lds[buf][8192 + t * 16]);
    };
    auto stageB01 = [&](int buf, int kt) {
        load_lds16(Bb + bsrc[0] + kt * 128, &lds[buf][16384 + t * 16]);
        load_lds16(Bb + bsrc[1] + kt * 128, &lds[buf][24576 + t * 16]);
    };
    auto stageB23 = [&](int buf, int kt) {
        load_lds16(Bb + bsrc[2] + kt * 128, &lds[buf][32768 + t * 16]);
        load_lds16(Bb + bsrc[3] + kt * 128, &lds[buf][40960 + t * 16]);
    };

    // ---- fragment read addressing (swizzled) ----
    const int lm = lane & 15, lk = lane >> 4;
    const int swz = (lane & 7) << 4;
    const int co0 = (lk * 16) ^ swz;               // kk=0 column-bytes
    const int co1 = (64 + lk * 16) ^ swz;          // kk=1

    f32x4 acc[4][4] = {};
    const int nt = K >> 6;

    // ---- prologue: tiles 0 and 1 in flight ----
    stageA(0, 0); stageB01(0, 0); stageB23(0, 0);
    stageA(1, 1); stageB01(1, 1); stageB23(1, 1);
    asm volatile("s_waitcnt vmcnt(6)" ::: "memory");      // tile 0 landed
    __builtin_amdgcn_s_barrier();

    for (int kt = 0; kt < nt; ++kt) {
        const int buf = kt % 3;
        const int nb = (kt + 2) % 3;
        const bool pf = (kt + 2) < nt;
        bf16x8 a[4][2], b[2][2];

        // ======== phase 1: n-half 0 ========
        #pragma unroll
        for (int m = 0; m < 4; ++m) {
            const int rb = (wr * 64 + m * 16 + lm) * 128;
            a[m][0] = *(const bf16x8*)&lds[buf][rb + co0];
            a[m][1] = *(const bf16x8*)&lds[buf][rb + co1];
        }
        #pragma unroll
        for (int n = 0; n < 2; ++n) {
            const int rb = 16384 + (wc * 64 + n * 16 + lm) * 128;
            b[n][0] = *(const bf16x8*)&lds[buf][rb + co0];
            b[n][1] = *(const bf16x8*)&lds[buf][rb + co1];
        }
        if (pf) { stageA(nb, kt + 2); stageB01(nb, kt + 2); }
        __builtin_amdgcn_s_barrier();
        asm volatile("s_waitcnt lgkmcnt(0)" ::: "memory");
        __builtin_amdgcn_sched_barrier(0);
        __builtin_amdgcn_s_setprio(1);
        #pragma unroll
        for (int m = 0; m < 4; ++m)
            #pragma unroll
            for (int n = 0; n < 2; ++n) {
                acc[m][n] = __builtin_amdgcn_mfma_f32_16x16x32_bf16(a[m][0], b[n][0], acc[m][n], 0, 0, 0);
                acc[m][n] = __builtin_amdgcn_mfma_f32_16x16x32_bf16(a[m][1], b[n][1], acc[m][n], 0, 0, 0);
            }
        __builtin_amdgcn_s_setprio(0);
        __builtin_amdgcn_s_barrier();

        // ======== phase 2: n-half 1 ========
        #pragma unroll
        for (int n = 0; n < 2; ++n) {
            const int rb = 16384 + (wc * 64 + 32 + n * 16 + lm) * 128;
            b[n][0] = *(const bf16x8*)&lds[buf][rb + co0];
            b[n][1] = *(const bf16x8*)&lds[buf][rb + co1];
        }
        if (pf) stageB23(nb, kt + 2);
        __builtin_amdgcn_s_barrier();
        asm volatile("s_waitcnt lgkmcnt(0)" ::: "memory");
        __builtin_amdgcn_sched_barrier(0);
        __builtin_amdgcn_s_setprio(1);
        #pragma unroll
        for (int m = 0; m < 4; ++m)
            #pragma unroll
            for (int n = 0; n < 2; ++n) {
                acc[m][2 + n] = __builtin_amdgcn_mfma_f32_16x16x32_bf16(a[m][0], b[n][0], acc[m][2 + n], 0, 0, 0);
                acc[m][2 + n] = __builtin_amdgcn_mfma_f32_16x16x32_bf16(a[m][1], b[n][1], acc[m][2 + n], 0, 0, 0);
            }
        __builtin_amdgcn_s_setprio(0);
        // counted vmcnt: next tile (kt+1) must have landed; tile kt+2 (6 loads)
        // may stay in flight.  Tail: nothing was issued, drain to 0.
        if (kt + 1 < nt) {
            if (pf) asm volatile("s_waitcnt vmcnt(6)" ::: "memory");
            else    asm volatile("s_waitcnt vmcnt(0)" ::: "memory");
        }
        __builtin_amdgcn_s_barrier();
    }

    // ---- epilogue ----
    #pragma unroll
    for (int m = 0; m < 4; ++m)
      #pragma unroll
      for (int n = 0; n < 4; ++n)
        #pragma unroll
        for (int r = 0; r < 4; ++r) {
            const int grow = bm * 128 + wr * 64 + m * 16 + lk * 4 + r;
            const int gcol = bn * 256 + wc * 64 + n * 16 + lm;
            const float v = acc[m][n][r];
            if constexpr (EPI == 0) {
                ((short*)outp)[(long)grow * N + gcol] = to_bf16s(v);
            } else if constexpr (EPI == 2) {
                const long i = (long)grow * N + gcol;
                ((float*)outp)[i] = res[i] + v;
            } else if constexpr (EPI == 4) {
                const long i = (long)grow * N + gcol;
                const float g = bf16s_to_f(aux[i]);
                const float sw = g / (1.f + __expf(-g));
                ((short*)outp)[i] = to_bf16s(sw * v);
            } else {  // EPI 5: QKV split
                if (gcol < 2048)
                    ((short*)outp)[(long)grow * 2048 + gcol] = to_bf16s(v);
                else
                    outp2[(long)(gcol - 2048) * 8192 + grow] = to_bf16s(v);
            }
        }
}

// ---------------------------------------------------------------------------
// Windowed causal attention (WINDOW=64, D=1024).  32 queries / block,
// 96-key span.  Q,K bf16 rows of stride ldq; VT bf16 [1024][8192]; att bf16.
// ---------------------------------------------------------------------------
__global__ __launch_bounds__(128)
void attn_kernel(const short* __restrict__ Q, const short* __restrict__ Km,
                 int ldq, const short* __restrict__ VT, short* __restrict__ att) {
    const int T = 2048, D = 1024, Mtot = 8192;
    const int bid = blockIdx.x;
    const int b = bid >> 6;
    const int q0 = (bid & 63) << 5;
    const long qrow0 = (long)b * T + q0;
    const int t = threadIdx.x, lane = t & 63, w = t >> 6;

    __shared__ short Qs[32 * 32];
    __shared__ short Ks[96 * 32];
    __shared__ float S_lds[32][100];
    __shared__ short P_lds[32 * 96];
    __shared__ short VTs[128 * 96];

    // ---- S = Q K^T over K=1024 ----
    f32x4 s[6] = {};
    const int trow = t >> 2, tk8 = (t & 3) * 8;
    for (int kt = 0; kt < 32; ++kt) {
        const int k0 = kt << 5;
        load_lds16(Q + (qrow0 + trow) * ldq + k0 + tk8, &Qs[t * 8]);
        #pragma unroll
        for (int s2 = 0; s2 < 3; ++s2) {
            const int krow = s2 * 32 + trow;
            int j = q0 - 64 + krow; if (j < 0) j = 0;
            load_lds16(Km + ((long)b * T + j) * ldq + k0 + tk8, &Ks[(s2 * 128 + t) * 8]);
        }
        __syncthreads();
        const int ko = (lane >> 4) * 8;
        const bf16x8 aq = *(const bf16x8*)&Qs[(w * 16 + (lane & 15)) * 32 + ko];
        #pragma unroll
        for (int n = 0; n < 6; ++n) {
            const bf16x8 bk = *(const bf16x8*)&Ks[(n * 16 + (lane & 15)) * 32 + ko];
            s[n] = __builtin_amdgcn_mfma_f32_16x16x32_bf16(aq, bk, s[n], 0, 0, 0);
        }
        __syncthreads();
    }
    #pragma unroll
    for (int n = 0; n < 6; ++n)
        #pragma unroll
        for (int r = 0; r < 4; ++r)
            S_lds[w * 16 + ((lane >> 4) << 2) + r][n * 16 + (lane & 15)] = s[n][r] * 0.03125f;
    __syncthreads();

    // ---- masked softmax ----
    {
        const int row = t >> 2, c0 = (t & 3) * 24;
        float e[24];
        float mx = -1e30f;
        #pragma unroll
        for (int c = 0; c < 24; ++c) {
            const int kj = c0 + c;
            const bool valid = (kj > row) && (kj <= row + 64) && (q0 - 64 + kj >= 0);
            const float sv = valid ? S_lds[row][kj] : -1e30f;
            e[c] = sv;
            mx = fmaxf(mx, sv);
        }
        mx = fmaxf(mx, __shfl_xor(mx, 1));
        mx = fmaxf(mx, __shfl_xor(mx, 2));
        float sum = 0.f;
        #pragma unroll
        for (int c = 0; c < 24; ++c) {
            const float ev = (e[c] > -1e29f) ? __expf(e[c] - mx) : 0.f;
            e[c] = ev; sum += ev;
        }
        sum += __shfl_xor(sum, 1);
        sum += __shfl_xor(sum, 2);
        const float inv = 1.f / sum;
        #pragma unroll
        for (int c = 0; c < 24; ++c)
            P_lds[row * 96 + c0 + c] = to_bf16s(e[c] * inv);
    }
    __syncthreads();

    // ---- attended = P V ----
    bf16x8 pa[3];
    {
        const int ko = (lane >> 4) * 8;
        #pragma unroll
        for (int kc = 0; kc < 3; ++kc)
            pa[kc] = *(const bf16x8*)&P_lds[(w * 16 + (lane & 15)) * 96 + kc * 32 + ko];
    }
    for (int dc = 0; dc < 8; ++dc) {
        #pragma unroll
        for (int s2 = 0; s2 < 12; ++s2) {
            const int idx = s2 * 128 + t;
            const int dr = idx / 12, c = idx - dr * 12;
            int j = q0 - 64 + c * 8; if (j < 0) j = 0;
            load_lds16(VT + (long)(dc * 128 + dr) * Mtot + b * T + j, &VTs[idx * 8]);
        }
        __syncthreads();
        f32x4 o[8] = {};
        const int ko = (lane >> 4) * 8;
        #pragma unroll
        for (int kc = 0; kc < 3; ++kc)
            #pragma unroll
            for (int n = 0; n < 8; ++n) {
                const bf16x8 vb = *(const bf16x8*)&VTs[(n * 16 + (lane & 15)) * 96 + kc * 32 + ko];
                o[n] = __builtin_amdgcn_mfma_f32_16x16x32_bf16(pa[kc], vb, o[n], 0, 0, 0);
            }
        __syncthreads();
        #pragma unroll
        for (int n = 0; n < 8; ++n)
            #pragma unroll
            for (int r = 0; r < 4; ++r) {
                const long grow = qrow0 + w * 16 + ((lane >> 4) << 2) + r;
                const int gcol = dc * 128 + n * 16 + (lane & 15);
                att[grow * D + gcol] = to_bf16s(o[n][r]);
            }
    }
}

// ---------------------------------------------------------------------------
extern "C" void kernel_launch(void* const* d_in, const int* in_sizes, int n_in,
                              void* d_out, int out_size, void* d_ws, size_t ws_size,
                              hipStream_t stream) {
    const float* x   = (const float*)d_in[0];
    const float* n1w = (const float*)d_in[1];
    const float* n2w = (const float*)d_in[2];
    const float* Wq  = (const float*)d_in[3];
    const float* Wk  = (const float*)d_in[4];
    const float* Wv  = (const float*)d_in[5];
    const float* Wo  = (const float*)d_in[6];
    const float* W1  = (const float*)d_in[7];
    const float* W2  = (const float*)d_in[8];
    const float* W3  = (const float*)d_in[9];

    const int M = 8192;           // B*T
    char* ws = (char*)d_ws;
    size_t off = 0;
    auto alloc = [&](size_t bytes) { void* p = ws + off; off += (bytes + 255) & ~(size_t)255; return p; };

    short* xn1 = (short*)alloc((size_t)M * 1024 * 2);   // reused as att
    short* qk  = (short*)alloc((size_t)M * 2048 * 2);   // q | k interleaved rows (ld=2048)
    short* vT  = (short*)alloc((size_t)M * 1024 * 2);   // V^T [1024][8192]
    float* x2  = (float*)alloc((size_t)M * 1024 * 4);
    short* WqT = (short*)alloc((size_t)1024 * 1024 * 2);   // WqT,WkT,WvT contiguous ->
    short* WkT = (short*)alloc((size_t)1024 * 1024 * 2);   //   [3072][1024] fused QKV weight
    short* WvT = (short*)alloc((size_t)1024 * 1024 * 2);
    short* WoT = (short*)alloc((size_t)1024 * 1024 * 2);
    short* W1T = (short*)alloc((size_t)2048 * 1024 * 2);
    short* W3T = (short*)alloc((size_t)2048 * 1024 * 2);
    short* W2T = (short*)alloc((size_t)1024 * 2048 * 2);
    short* att = xn1;                                   // xn1 dead after QKV
    short* xn2 = qk;                                    // q/k dead after attention
    short* g1  = qk + (size_t)M * 1024;                 // spans qk 2nd half + vT (33.5MB)

    transpose_all<<<10240, 256, 0, stream>>>(Wq, Wk, Wv, Wo, W1, W3, W2,
                                             WqT, WkT, WvT, WoT, W1T, W3T, W2T);

    // norm1 -> xn1 (bf16)
    rmsnorm_kernel<<<M, 256, 0, stream>>>(x, n1w, xn1);
    // fused QKV: [M,3072] ; cols<2048 -> qk (ld 2048), cols>=2048 -> vT transposed
    gemm8p<5><<<dim3(12, 64), 512, 0, stream>>>(xn1, WqT, nullptr, nullptr, qk, vT, M, 3072, 1024);
    // attention -> att (bf16)
    attn_kernel<<<256, 128, 0, stream>>>(qk, qk + 1024, 2048, vT, att);
    // x2 = x + att @ Wo   (fp32)
    gemm8p<2><<<dim3(4, 64), 512, 0, stream>>>(att, WoT, nullptr, x, x2, nullptr, M, 1024, 1024);
    // norm2 -> xn2 (bf16)
    rmsnorm_kernel<<<M, 256, 0, stream>>>(x2, n2w, xn2);
    // g1 = xn2 @ W1   (bf16)
    gemm8p<0><<<dim3(8, 64), 512, 0, stream>>>(xn2, W1T, nullptr, nullptr, g1, nullptr, M, 2048, 1024);
    // h = silu(g1) * (xn2 @ W3)   (bf16, in-place over g1)
    gemm8p<4><<<dim3(8, 64), 512, 0, stream>>>(xn2, W3T, g1, nullptr, g1, nullptr, M, 2048, 1024);
    // out = x2 + h @ W2   (fp32)
    gemm8p<2><<<dim3(4, 64), 512, 0, stream>>>(g1, W2T, nullptr, x2, (float*)d_out, nullptr, M, 1024, 2048);
}

// Round 4
// 317.340 us; speedup vs baseline: 1.3285x; 1.0333x over previous
//
#include <hip/hip_runtime.h>
#include <hip/hip_bf16.h>

typedef __attribute__((ext_vector_type(8))) short bf16x8;
typedef __attribute__((ext_vector_type(4))) float f32x4;

__device__ __forceinline__ short to_bf16s(float f) {
    union { __hip_bfloat16 h; short s; } u;
    u.h = __float2bfloat16(f);
    return u.s;
}

__device__ __forceinline__ float bf16s_to_f(short s) {
    union { float f; unsigned u; } cv;
    cv.u = ((unsigned)(unsigned short)s) << 16;
    return cv.f;
}

__device__ __forceinline__ void load_lds16(const void* g, void* l) {
    __builtin_amdgcn_global_load_lds((const __attribute__((address_space(1))) void*)g,
                                     (__attribute__((address_space(3))) void*)l, 16, 0, 0);
}

// ---------------------------------------------------------------------------
// All 7 weight transposes (fp32 [K][N] -> bf16 [N][K]) in one launch.
// ---------------------------------------------------------------------------
__global__ __launch_bounds__(256)
void transpose_all(const float* __restrict__ Wq, const float* __restrict__ Wk,
                   const float* __restrict__ Wv, const float* __restrict__ Wo,
                   const float* __restrict__ W1, const float* __restrict__ W3,
                   const float* __restrict__ W2,
                   short* __restrict__ WqT, short* __restrict__ WkT,
                   short* __restrict__ WvT, short* __restrict__ WoT,
                   short* __restrict__ W1T, short* __restrict__ W3T,
                   short* __restrict__ W2T) {
    __shared__ float tile[32][33];
    const int bid = blockIdx.x;
    const float* src; short* dst; int K, N, tl;
    if (bid < 4096) {
        const int wi = bid >> 10; tl = bid & 1023;
        src = wi == 0 ? Wq : wi == 1 ? Wk : wi == 2 ? Wv : Wo;
        dst = wi == 0 ? WqT : wi == 1 ? WkT : wi == 2 ? WvT : WoT;
        K = 1024; N = 1024;
    } else if (bid < 8192) {
        const int wi = (bid - 4096) >> 11; tl = (bid - 4096) & 2047;
        src = wi ? W3 : W1; dst = wi ? W3T : W1T;
        K = 1024; N = 2048;
    } else {
        tl = bid - 8192; src = W2; dst = W2T;
        K = 2048; N = 1024;
    }
    const int nx = N >> 5;
    const int n0 = (tl % nx) * 32, k0 = (tl / nx) * 32;
    const int t = threadIdx.x;
    {
        const int lr = t >> 3, lc = (t & 7) * 4;
        float4 v = *(const float4*)&src[(long)(k0 + lr) * N + n0 + lc];
        tile[lr][lc] = v.x; tile[lr][lc + 1] = v.y;
        tile[lr][lc + 2] = v.z; tile[lr][lc + 3] = v.w;
    }
    __syncthreads();
    {
        const int nr = t >> 3, kc = (t & 7) * 4;
        short4 o;
        o.x = to_bf16s(tile[kc][nr]);
        o.y = to_bf16s(tile[kc + 1][nr]);
        o.z = to_bf16s(tile[kc + 2][nr]);
        o.w = to_bf16s(tile[kc + 3][nr]);
        *(short4*)&dst[(long)(n0 + nr) * K + k0 + kc] = o;
    }
}

// ---------------------------------------------------------------------------
// RMSNorm (fp32 in) -> bf16 out.  One block per row, D=1024.
// ---------------------------------------------------------------------------
__global__ __launch_bounds__(256)
void rmsnorm_kernel(const float* __restrict__ x, const float* __restrict__ wt,
                    short* __restrict__ out) {
    const int D = 1024;
    const long row = blockIdx.x;
    const int t = threadIdx.x;
    float4 v = ((const float4*)(x + row * D))[t];
    float ss = v.x * v.x + v.y * v.y + v.z * v.z + v.w * v.w;
    #pragma unroll
    for (int off = 32; off; off >>= 1) ss += __shfl_xor(ss, off);
    __shared__ float red[4];
    if ((t & 63) == 0) red[t >> 6] = ss;
    __syncthreads();
    ss = red[0] + red[1] + red[2] + red[3];
    const float inv = rsqrtf(ss * (1.0f / 1024.0f) + 1e-6f);
    float4 wv = ((const float4*)wt)[t];
    short4 o;
    o.x = to_bf16s(v.x * inv * wv.x);
    o.y = to_bf16s(v.y * inv * wv.y);
    o.z = to_bf16s(v.z * inv * wv.z);
    o.w = to_bf16s(v.w * inv * wv.w);
    *(short4*)&out[row * D + t * 4] = o;
}

// ---------------------------------------------------------------------------
// 256x256-tile bf16 MFMA GEMM, m201-style 8-phase schedule.
// BK=64, 512 threads = 8 waves (2 wr x 4 wc), per-wave C 128x64.
// LDS 128 KiB: [A|B] x 2 dbuf x 2 half(128 rows x 64k).  T2 XOR-swizzle via
// inverse-swizzled global source + swizzled ds_read (involution, rule #21).
// One half-tile (2 x global_load_lds) staged per phase; vmcnt(4) at phases
// 4 and 8 only.  Snake quadrant order m0n0 -> m0n1 -> m1n1 -> m1n0.
// T1 bijective XCD chunk swizzle on the 1-D block index.
// A[M][K] bf16, B[N][K] bf16.
// EPI 0: bf16 C[M][N]          2: fp32 out = res + C
// EPI 4: bf16 out = silu(aux)*C (in-place over aux)
// EPI 5: QKV split: cols<2048 -> bf16 outp[row][2048]; cols>=2048 ->
//        transposed bf16 outp2[col-2048][8192]
// ---------------------------------------------------------------------------
#define MFMA16(MB, NB, BREG)                                                   \
    __builtin_amdgcn_s_barrier();                                              \
    asm volatile("s_waitcnt lgkmcnt(0)" ::: "memory");                         \
    __builtin_amdgcn_sched_barrier(0);                                         \
    __builtin_amdgcn_s_setprio(1);                                             \
    _Pragma("unroll")                                                          \
    for (int m_ = 0; m_ < 4; ++m_)                                             \
        _Pragma("unroll")                                                      \
        for (int n_ = 0; n_ < 2; ++n_) {                                       \
            acc[(MB) + m_][(NB) + n_] = __builtin_amdgcn_mfma_f32_16x16x32_bf16( \
                a[m_][0], BREG[n_][0], acc[(MB) + m_][(NB) + n_], 0, 0, 0);    \
            acc[(MB) + m_][(NB) + n_] = __builtin_amdgcn_mfma_f32_16x16x32_bf16( \
                a[m_][1], BREG[n_][1], acc[(MB) + m_][(NB) + n_], 0, 0, 0);    \
        }                                                                      \
    __builtin_amdgcn_s_setprio(0);                                             \
    __builtin_amdgcn_s_barrier();

#define READA(BUF, MG)                                                         \
    _Pragma("unroll")                                                          \
    for (int m_ = 0; m_ < 4; ++m_) {                                           \
        const int rih_ = ((MG) * 4 + m_) * 16 + lm;                            \
        const int rb_ = ((BUF) * 2 + wr) * 16384 + rih_ * 128;                 \
        a[m_][0] = *(const bf16x8*)&lds[rb_ + ((lk * 16) ^ sw)];               \
        a[m_][1] = *(const bf16x8*)&lds[rb_ + ((64 + lk * 16) ^ sw)];          \
    }

#define READB(BUF, NH, ARR)                                                    \
    _Pragma("unroll")                                                          \
    for (int n_ = 0; n_ < 2; ++n_) {                                           \
        const int rih_ = (wc & 1) * 64 + ((NH) * 2 + n_) * 16 + lm;            \
        const int rb_ = 65536 + ((BUF) * 2 + (wc >> 1)) * 16384 + rih_ * 128;  \
        ARR[n_][0] = *(const bf16x8*)&lds[rb_ + ((lk * 16) ^ sw)];             \
        ARR[n_][1] = *(const bf16x8*)&lds[rb_ + ((64 + lk * 16) ^ sw)];        \
    }

template<int EPI>
__global__ __launch_bounds__(512, 2)
void gemm256(const short* __restrict__ A, const short* __restrict__ B0,
             const short* __restrict__ aux, const float* __restrict__ res,
             void* __restrict__ outp, short* __restrict__ outp2,
             int M, int N, int K) {
    __shared__ __align__(16) char lds[131072];

    const int t = threadIdx.x;
    const int lane = t & 63, w = t >> 6;
    const int wr = w >> 2, wc = w & 3;
    const int lm = lane & 15, lk = lane >> 4;
    const int sw = (lm & 7) << 4;

    // ---- T1 bijective XCD chunk swizzle (nwg % 8 == 0 for all our grids) ----
    const int nbn = N >> 8;
    const int nwg = gridDim.x;
    const int chunk = nwg >> 3;
    const int logical = (blockIdx.x & 7) * chunk + (blockIdx.x >> 3);
    const int bm = logical / nbn, bn = logical - (logical / nbn) * nbn;

    const long Kb = (long)K * 2;
    const char* Ab = (const char*)A;
    const char* Bb = (const char*)B0;

    // ---- staging sources (inverse-swizzled global addresses) ----
    long srcA[2][2], srcB[2][2];
    {
        const int rowp = t >> 3;              // + c*64 added below
        const int cbx = (t & 7) * 16;
        const int swz = ((t >> 3) & 7) << 4;  // (row & 7) invariant to c*64
        #pragma unroll
        for (int h = 0; h < 2; ++h)
            #pragma unroll
            for (int c = 0; c < 2; ++c) {
                srcA[h][c] = (long)(bm * 256 + h * 128 + c * 64 + rowp) * Kb + (cbx ^ swz);
                srcB[h][c] = (long)(bn * 256 + h * 128 + c * 64 + rowp) * Kb + (cbx ^ swz);
            }
    }
    auto stA = [&](int kt, int h) {
        const int buf = kt & 1;
        #pragma unroll
        for (int c = 0; c < 2; ++c)
            load_lds16(Ab + srcA[h][c] + (long)kt * 128,
                       &lds[(buf * 2 + h) * 16384 + c * 8192 + t * 16]);
    };
    auto stB = [&](int kt, int h) {
        const int buf = kt & 1;
        #pragma unroll
        for (int c = 0; c < 2; ++c)
            load_lds16(Bb + srcB[h][c] + (long)kt * 128,
                       &lds[65536 + (buf * 2 + h) * 16384 + c * 8192 + t * 16]);
    };

    f32x4 acc[8][4] = {};
    bf16x8 a[4][2], b0[2][2], b1[2][2];
    const int nt = K >> 6;                    // K-tiles (always even here)

    // ---- prologue: tile 0 fully + B of tile 1 ----
    stB(0, 0); stB(0, 1); stA(0, 0); stA(0, 1); stB(1, 0); stB(1, 1);
    asm volatile("s_waitcnt vmcnt(4)" ::: "memory");   // tile 0 landed
    __builtin_amdgcn_s_barrier();

    for (int kt0 = 0; kt0 < nt; kt0 += 2) {
        const int kt1 = kt0 + 1;
        const bool pf = (kt0 + 2) < nt;

        // p1: (m0,n0) of tile kt0
        READA(0, 0); READB(0, 0, b0);
        stA(kt1, 0);
        MFMA16(0, 0, b0)
        // p2: (m0,n1)
        READB(0, 1, b1);
        stA(kt1, 1);
        MFMA16(0, 2, b1)
        // p3: (m1,n1)
        READA(0, 1);
        if (pf) stB(kt0 + 2, 0);
        MFMA16(4, 2, b1)
        // p4: (m1,n0)  [checkpoint C1]
        if (pf) { stB(kt0 + 2, 1); asm volatile("s_waitcnt vmcnt(4)" ::: "memory"); }
        else    { asm volatile("s_waitcnt vmcnt(0)" ::: "memory"); }
        MFMA16(4, 0, b0)
        // p5: (m0,n0) of tile kt1
        READA(1, 0); READB(1, 0, b0);
        if (pf) stA(kt0 + 2, 0);
        MFMA16(0, 0, b0)
        // p6: (m0,n1)
        READB(1, 1, b1);
        if (pf) stA(kt0 + 2, 1);
        MFMA16(0, 2, b1)
        // p7: (m1,n1)
        READA(1, 1);
        if (pf) stB(kt1 + 2, 0);
        MFMA16(4, 2, b1)
        // p8: (m1,n0)  [checkpoint C2]
        if (pf) { stB(kt1 + 2, 1); asm volatile("s_waitcnt vmcnt(4)" ::: "memory"); }
        else    { asm volatile("s_waitcnt vmcnt(0)" ::: "memory"); }
        MFMA16(4, 0, b0)
    }

    // ---- epilogue ----
    #pragma unroll
    for (int mf = 0; mf < 8; ++mf)
      #pragma unroll
      for (int nf = 0; nf < 4; ++nf)
        #pragma unroll
        for (int r = 0; r < 4; ++r) {
            const int grow = bm * 256 + wr * 128 + mf * 16 + lk * 4 + r;
            const int gcol = bn * 256 + wc * 64 + nf * 16 + lm;
            const float v = acc[mf][nf][r];
            if constexpr (EPI == 0) {
                ((short*)outp)[(long)grow * N + gcol] = to_bf16s(v);
            } else if constexpr (EPI == 2) {
                const long i = (long)grow * N + gcol;
                ((float*)outp)[i] = res[i] + v;
            } else if constexpr (EPI == 4) {
                const long i = (long)grow * N + gcol;
                const float g = bf16s_to_f(aux[i]);
                const float sws = g / (1.f + __expf(-g));
                ((short*)outp)[i] = to_bf16s(sws * v);
            } else {  // EPI 5: QKV split
                if (gcol < 2048)
                    ((short*)outp)[(long)grow * 2048 + gcol] = to_bf16s(v);
                else
                    outp2[(long)(gcol - 2048) * 8192 + grow] = to_bf16s(v);
            }
        }
}

// ---------------------------------------------------------------------------
// Windowed causal attention (WINDOW=64, D=1024).  32 queries / block,
// 96-key span.  Q,K bf16 rows of stride ldq; VT bf16 [1024][8192]; att bf16.
// ---------------------------------------------------------------------------
__global__ __launch_bounds__(128)
void attn_kernel(const short* __restrict__ Q, const short* __restrict__ Km,
                 int ldq, const short* __restrict__ VT, short* __restrict__ att) {
    const int T = 2048, D = 1024, Mtot = 8192;
    const int bid = blockIdx.x;
    const int b = bid >> 6;
    const int q0 = (bid & 63) << 5;
    const long qrow0 = (long)b * T + q0;
    const int t = threadIdx.x, lane = t & 63, w = t >> 6;

    __shared__ short Qs[32 * 32];
    __shared__ short Ks[96 * 32];
    __shared__ float S_lds[32][100];
    __shared__ short P_lds[32 * 96];
    __shared__ short VTs[128 * 96];

    f32x4 s[6] = {};
    const int trow = t >> 2, tk8 = (t & 3) * 8;
    for (int kt = 0; kt < 32; ++kt) {
        const int k0 = kt << 5;
        load_lds16(Q + (qrow0 + trow) * ldq + k0 + tk8, &Qs[t * 8]);
        #pragma unroll
        for (int s2 = 0; s2 < 3; ++s2) {
            const int krow = s2 * 32 + trow;
            int j = q0 - 64 + krow; if (j < 0) j = 0;
            load_lds16(Km + ((long)b * T + j) * ldq + k0 + tk8, &Ks[(s2 * 128 + t) * 8]);
        }
        __syncthreads();
        const int ko = (lane >> 4) * 8;
        const bf16x8 aq = *(const bf16x8*)&Qs[(w * 16 + (lane & 15)) * 32 + ko];
        #pragma unroll
        for (int n = 0; n < 6; ++n) {
            const bf16x8 bk = *(const bf16x8*)&Ks[(n * 16 + (lane & 15)) * 32 + ko];
            s[n] = __builtin_amdgcn_mfma_f32_16x16x32_bf16(aq, bk, s[n], 0, 0, 0);
        }
        __syncthreads();
    }
    #pragma unroll
    for (int n = 0; n < 6; ++n)
        #pragma unroll
        for (int r = 0; r < 4; ++r)
            S_lds[w * 16 + ((lane >> 4) << 2) + r][n * 16 + (lane & 15)] = s[n][r] * 0.03125f;
    __syncthreads();

    {
        const int row = t >> 2, c0 = (t & 3) * 24;
        float e[24];
        float mx = -1e30f;
        #pragma unroll
        for (int c = 0; c < 24; ++c) {
            const int kj = c0 + c;
            const bool valid = (kj > row) && (kj <= row + 64) && (q0 - 64 + kj >= 0);
            const float sv = valid ? S_lds[row][kj] : -1e30f;
            e[c] = sv;
            mx = fmaxf(mx, sv);
        }
        mx = fmaxf(mx, __shfl_xor(mx, 1));
        mx = fmaxf(mx, __shfl_xor(mx, 2));
        float sum = 0.f;
        #pragma unroll
        for (int c = 0; c < 24; ++c) {
            const float ev = (e[c] > -1e29f) ? __expf(e[c] - mx) : 0.f;
            e[c] = ev; sum += ev;
        }
        sum += __shfl_xor(sum, 1);
        sum += __shfl_xor(sum, 2);
        const float inv = 1.f / sum;
        #pragma unroll
        for (int c = 0; c < 24; ++c)
            P_lds[row * 96 + c0 + c] = to_bf16s(e[c] * inv);
    }
    __syncthreads();

    bf16x8 pa[3];
    {
        const int ko = (lane >> 4) * 8;
        #pragma unroll
        for (int kc = 0; kc < 3; ++kc)
            pa[kc] = *(const bf16x8*)&P_lds[(w * 16 + (lane & 15)) * 96 + kc * 32 + ko];
    }
    for (int dc = 0; dc < 8; ++dc) {
        #pragma unroll
        for (int s2 = 0; s2 < 12; ++s2) {
            const int idx = s2 * 128 + t;
            const int dr = idx / 12, c = idx - dr * 12;
            int j = q0 - 64 + c * 8; if (j < 0) j = 0;
            load_lds16(VT + (long)(dc * 128 + dr) * Mtot + b * T + j, &VTs[idx * 8]);
        }
        __syncthreads();
        f32x4 o[8] = {};
        const int ko = (lane >> 4) * 8;
        #pragma unroll
        for (int kc = 0; kc < 3; ++kc)
            #pragma unroll
            for (int n = 0; n < 8; ++n) {
                const bf16x8 vb = *(const bf16x8*)&VTs[(n * 16 + (lane & 15)) * 96 + kc * 32 + ko];
                o[n] = __builtin_amdgcn_mfma_f32_16x16x32_bf16(pa[kc], vb, o[n], 0, 0, 0);
            }
        __syncthreads();
        #pragma unroll
        for (int n = 0; n < 8; ++n)
            #pragma unroll
            for (int r = 0; r < 4; ++r) {
                const long grow = qrow0 + w * 16 + ((lane >> 4) << 2) + r;
                const int gcol = dc * 128 + n * 16 + (lane & 15);
                att[grow * D + gcol] = to_bf16s(o[n][r]);
            }
    }
}

// ---------------------------------------------------------------------------
extern "C" void kernel_launch(void* const* d_in, const int* in_sizes, int n_in,
                              void* d_out, int out_size, void* d_ws, size_t ws_size,
                              hipStream_t stream) {
    const float* x   = (const float*)d_in[0];
    const float* n1w = (const float*)d_in[1];
    const float* n2w = (const float*)d_in[2];
    const float* Wq  = (const float*)d_in[3];
    const float* Wk  = (const float*)d_in[4];
    const float* Wv  = (const float*)d_in[5];
    const float* Wo  = (const float*)d_in[6];
    const float* W1  = (const float*)d_in[7];
    const float* W2  = (const float*)d_in[8];
    const float* W3  = (const float*)d_in[9];

    const int M = 8192;           // B*T
    char* ws = (char*)d_ws;
    size_t off = 0;
    auto alloc = [&](size_t bytes) { void* p = ws + off; off += (bytes + 255) & ~(size_t)255; return p; };

    short* xn1 = (short*)alloc((size_t)M * 1024 * 2);   // reused as att
    short* qk  = (short*)alloc((size_t)M * 2048 * 2);   // q | k interleaved rows (ld=2048)
    short* vT  = (short*)alloc((size_t)M * 1024 * 2);   // V^T [1024][8192]
    float* x2  = (float*)alloc((size_t)M * 1024 * 4);
    short* WqT = (short*)alloc((size_t)1024 * 1024 * 2);   // WqT,WkT,WvT contiguous ->
    short* WkT = (short*)alloc((size_t)1024 * 1024 * 2);   //   [3072][1024] fused QKV weight
    short* WvT = (short*)alloc((size_t)1024 * 1024 * 2);
    short* WoT = (short*)alloc((size_t)1024 * 1024 * 2);
    short* W1T = (short*)alloc((size_t)2048 * 1024 * 2);
    short* W3T = (short*)alloc((size_t)2048 * 1024 * 2);
    short* W2T = (short*)alloc((size_t)1024 * 2048 * 2);
    short* att = xn1;                                   // xn1 dead after QKV
    short* xn2 = qk;                                    // q/k dead after attention
    short* g1  = qk + (size_t)M * 1024;                 // spans qk 2nd half + vT (33.5MB)

    transpose_all<<<10240, 256, 0, stream>>>(Wq, Wk, Wv, Wo, W1, W3, W2,
                                             WqT, WkT, WvT, WoT, W1T, W3T, W2T);

    // norm1 -> xn1 (bf16)
    rmsnorm_kernel<<<M, 256, 0, stream>>>(x, n1w, xn1);
    // fused QKV: [M,3072]; cols<2048 -> qk (ld 2048), cols>=2048 -> vT transposed
    gemm256<5><<<384, 512, 0, stream>>>(xn1, WqT, nullptr, nullptr, qk, vT, M, 3072, 1024);
    // attention -> att (bf16)
    attn_kernel<<<256, 128, 0, stream>>>(qk, qk + 1024, 2048, vT, att);
    // x2 = x + att @ Wo   (fp32)
    gemm256<2><<<128, 512, 0, stream>>>(att, WoT, nullptr, x, x2, nullptr, M, 1024, 1024);
    // norm2 -> xn2 (bf16)
    rmsnorm_kernel<<<M, 256, 0, stream>>>(x2, n2w, xn2);
    // g1 = xn2 @ W1   (bf16)
    gemm256<0><<<256, 512, 0, stream>>>(xn2, W1T, nullptr, nullptr, g1, nullptr, M, 2048, 1024);
    // h = silu(g1) * (xn2 @ W3)   (bf16, in-place over g1)
    gemm256<4><<<256, 512, 0, stream>>>(xn2, W3T, g1, nullptr, g1, nullptr, M, 2048, 1024);
    // out = x2 + h @ W2   (fp32)
    gemm256<2><<<128, 512, 0, stream>>>(g1, W2T, nullptr, x2, (float*)d_out, nullptr, M, 1024, 2048);
}

// Round 5
// 285.883 us; speedup vs baseline: 1.4746x; 1.1100x over previous
//
#include <hip/hip_runtime.h>
#include <hip/hip_bf16.h>

typedef __attribute__((ext_vector_type(8))) short bf16x8;
typedef __attribute__((ext_vector_type(4))) float f32x4;

__device__ __forceinline__ short to_bf16s(float f) {
    union { __hip_bfloat16 h; short s; } u;
    u.h = __float2bfloat16(f);
    return u.s;
}

__device__ __forceinline__ float bf16s_to_f(short s) {
    union { float f; unsigned u; } cv;
    cv.u = ((unsigned)(unsigned short)s) << 16;
    return cv.f;
}

__device__ __forceinline__ void load_lds16(const void* g, void* l) {
    __builtin_amdgcn_global_load_lds((const __attribute__((address_space(1))) void*)g,
                                     (__attribute__((address_space(3))) void*)l, 16, 0, 0);
}

// ---------------------------------------------------------------------------
// All 7 weight transposes (fp32 [K][N] -> bf16 [N][K]) in one launch.
// ---------------------------------------------------------------------------
__global__ __launch_bounds__(256)
void transpose_all(const float* __restrict__ Wq, const float* __restrict__ Wk,
                   const float* __restrict__ Wv, const float* __restrict__ Wo,
                   const float* __restrict__ W1, const float* __restrict__ W3,
                   const float* __restrict__ W2,
                   short* __restrict__ WqT, short* __restrict__ WkT,
                   short* __restrict__ WvT, short* __restrict__ WoT,
                   short* __restrict__ W1T, short* __restrict__ W3T,
                   short* __restrict__ W2T) {
    __shared__ float tile[32][33];
    const int bid = blockIdx.x;
    const float* src; short* dst; int K, N, tl;
    if (bid < 4096) {
        const int wi = bid >> 10; tl = bid & 1023;
        src = wi == 0 ? Wq : wi == 1 ? Wk : wi == 2 ? Wv : Wo;
        dst = wi == 0 ? WqT : wi == 1 ? WkT : wi == 2 ? WvT : WoT;
        K = 1024; N = 1024;
    } else if (bid < 8192) {
        const int wi = (bid - 4096) >> 11; tl = (bid - 4096) & 2047;
        src = wi ? W3 : W1; dst = wi ? W3T : W1T;
        K = 1024; N = 2048;
    } else {
        tl = bid - 8192; src = W2; dst = W2T;
        K = 2048; N = 1024;
    }
    const int nx = N >> 5;
    const int n0 = (tl % nx) * 32, k0 = (tl / nx) * 32;
    const int t = threadIdx.x;
    {
        const int lr = t >> 3, lc = (t & 7) * 4;
        float4 v = *(const float4*)&src[(long)(k0 + lr) * N + n0 + lc];
        tile[lr][lc] = v.x; tile[lr][lc + 1] = v.y;
        tile[lr][lc + 2] = v.z; tile[lr][lc + 3] = v.w;
    }
    __syncthreads();
    {
        const int nr = t >> 3, kc = (t & 7) * 4;
        short4 o;
        o.x = to_bf16s(tile[kc][nr]);
        o.y = to_bf16s(tile[kc + 1][nr]);
        o.z = to_bf16s(tile[kc + 2][nr]);
        o.w = to_bf16s(tile[kc + 3][nr]);
        *(short4*)&dst[(long)(n0 + nr) * K + k0 + kc] = o;
    }
}

// ---------------------------------------------------------------------------
// RMSNorm (fp32 in) -> bf16 out.  One block per row, D=1024.
// ---------------------------------------------------------------------------
__global__ __launch_bounds__(256)
void rmsnorm_kernel(const float* __restrict__ x, const float* __restrict__ wt,
                    short* __restrict__ out) {
    const int D = 1024;
    const long row = blockIdx.x;
    const int t = threadIdx.x;
    float4 v = ((const float4*)(x + row * D))[t];
    float ss = v.x * v.x + v.y * v.y + v.z * v.z + v.w * v.w;
    #pragma unroll
    for (int off = 32; off; off >>= 1) ss += __shfl_xor(ss, off);
    __shared__ float red[4];
    if ((t & 63) == 0) red[t >> 6] = ss;
    __syncthreads();
    ss = red[0] + red[1] + red[2] + red[3];
    const float inv = rsqrtf(ss * (1.0f / 1024.0f) + 1e-6f);
    float4 wv = ((const float4*)wt)[t];
    short4 o;
    o.x = to_bf16s(v.x * inv * wv.x);
    o.y = to_bf16s(v.y * inv * wv.y);
    o.z = to_bf16s(v.z * inv * wv.z);
    o.w = to_bf16s(v.w * inv * wv.w);
    *(short4*)&out[row * D + t * 4] = o;
}

// ---------------------------------------------------------------------------
// 256xBN-tile bf16 MFMA GEMM, m201-style 8-phase counted-vmcnt schedule.
// BNH=2: 256x256, 8 waves 2x4, per-wave 128x64, LDS 128K, vmcnt(4) @ C1/C2.
// BNH=1: 256x128, 8 waves 4x2, per-wave  64x64, LDS  96K, vmcnt(6) @ C1/C2.
// T2 XOR-swizzle: inverse-swizzled global source + swizzled ds_read.
// No sched_barrier / no memory clobber on lgkm (m141 lesson) — compiler keeps
// its own dependency waits; explicit fences only at vmcnt checkpoints.
// A[M][K] bf16, B[N][K] bf16.
// EPI 0: bf16 C[M][N]          2: fp32 out = res + C
// EPI 4: bf16 out = silu(aux)*C (in-place over aux)
// EPI 5: QKV split: cols<2048 -> bf16 outp[row][2048]; cols>=2048 ->
//        transposed bf16 outp2[col-2048][8192]
// ---------------------------------------------------------------------------
#define MFMA16(MB, NB, BREG)                                                   \
    __builtin_amdgcn_s_barrier();                                              \
    asm volatile("s_waitcnt lgkmcnt(0)");                                      \
    __builtin_amdgcn_s_setprio(1);                                             \
    _Pragma("unroll")                                                          \
    for (int m_ = 0; m_ < 4; ++m_)                                             \
        _Pragma("unroll")                                                      \
        for (int n_ = 0; n_ < 2; ++n_) {                                       \
            acc[(MB) + m_][(NB) + n_] = __builtin_amdgcn_mfma_f32_16x16x32_bf16( \
                a[m_][0], BREG[n_][0], acc[(MB) + m_][(NB) + n_], 0, 0, 0);    \
            acc[(MB) + m_][(NB) + n_] = __builtin_amdgcn_mfma_f32_16x16x32_bf16( \
                a[m_][1], BREG[n_][1], acc[(MB) + m_][(NB) + n_], 0, 0, 0);    \
        }                                                                      \
    __builtin_amdgcn_s_setprio(0);                                             \
    __builtin_amdgcn_s_barrier();

// BNH=2 fragment reads
#define READA2(BUF, MG)                                                        \
    _Pragma("unroll")                                                          \
    for (int m_ = 0; m_ < 4; ++m_) {                                           \
        const int rb_ = ((BUF) * 2 + wr) * 16384 + (((MG) * 4 + m_) * 16 + lm) * 128; \
        a[m_][0] = *(const bf16x8*)&lds[rb_ + ((lk * 16) ^ sw)];               \
        a[m_][1] = *(const bf16x8*)&lds[rb_ + ((64 + lk * 16) ^ sw)];          \
    }
#define READB2(BUF, NH, ARR)                                                   \
    _Pragma("unroll")                                                          \
    for (int n_ = 0; n_ < 2; ++n_) {                                           \
        const int rb_ = 65536 + ((BUF) * 2 + (wc >> 1)) * 16384 +              \
                        ((wc & 1) * 64 + ((NH) * 2 + n_) * 16 + lm) * 128;     \
        ARR[n_][0] = *(const bf16x8*)&lds[rb_ + ((lk * 16) ^ sw)];             \
        ARR[n_][1] = *(const bf16x8*)&lds[rb_ + ((64 + lk * 16) ^ sw)];        \
    }
// BNH=1 fragment reads
#define READA1(BUF)                                                            \
    _Pragma("unroll")                                                          \
    for (int m_ = 0; m_ < 4; ++m_) {                                           \
        const int rb_ = ((BUF) * 2 + (wr >> 1)) * 16384 +                      \
                        ((wr & 1) * 64 + m_ * 16 + lm) * 128;                  \
        a[m_][0] = *(const bf16x8*)&lds[rb_ + ((lk * 16) ^ sw)];               \
        a[m_][1] = *(const bf16x8*)&lds[rb_ + ((64 + lk * 16) ^ sw)];          \
    }
#define READB1(BUF, NG, ARR)                                                   \
    _Pragma("unroll")                                                          \
    for (int n_ = 0; n_ < 2; ++n_) {                                           \
        const int rb_ = 65536 + ((BUF) * 2 + wc) * 8192 +                      \
                        (((NG) * 2 + n_) * 16 + lm) * 128;                     \
        ARR[n_][0] = *(const bf16x8*)&lds[rb_ + ((lk * 16) ^ sw)];             \
        ARR[n_][1] = *(const bf16x8*)&lds[rb_ + ((64 + lk * 16) ^ sw)];        \
    }

template<int EPI, int BNH>
__global__ __launch_bounds__(512, 2)
void gemm256(const short* __restrict__ A, const short* __restrict__ B0,
             const short* __restrict__ aux, const float* __restrict__ res,
             void* __restrict__ outp, short* __restrict__ outp2,
             int M, int N, int K) {
    constexpr int BN = BNH * 128;
    __shared__ __align__(16) char lds[65536 + BNH * 32768];

    const int t = threadIdx.x;
    const int lane = t & 63, w = t >> 6;
    const int wr = (BNH == 2) ? (w >> 2) : (w >> 1);
    const int wc = (BNH == 2) ? (w & 3) : (w & 1);
    const int lm = lane & 15, lk = lane >> 4;
    const int sw = (lm & 7) << 4;

    // ---- T1 bijective XCD chunk swizzle (nwg % 8 == 0 for all our grids) ----
    const int nbn = N / BN;
    const int chunk = gridDim.x >> 3;
    const int logical = (blockIdx.x & 7) * chunk + (blockIdx.x >> 3);
    const int bm = logical / nbn, bn = logical - (logical / nbn) * nbn;

    const long Kb = (long)K * 2;
    const char* Ab = (const char*)A;
    const char* Bb = (const char*)B0;

    // ---- staging sources (inverse-swizzled global addresses) ----
    long srcA[2][2], srcB[2][BNH];
    {
        const int rowp = t >> 3;
        const int cbx = (t & 7) * 16;
        const int swz = ((t >> 3) & 7) << 4;
        #pragma unroll
        for (int h = 0; h < 2; ++h) {
            #pragma unroll
            for (int c = 0; c < 2; ++c)
                srcA[h][c] = (long)(bm * 256 + h * 128 + c * 64 + rowp) * Kb + (cbx ^ swz);
            #pragma unroll
            for (int c = 0; c < BNH; ++c)
                srcB[h][c] = (long)(bn * BN + h * (BN / 2) + c * 64 + rowp) * Kb + (cbx ^ swz);
        }
    }
    auto stA = [&](int kt, int h) {
        const int buf = kt & 1;
        #pragma unroll
        for (int c = 0; c < 2; ++c)
            load_lds16(Ab + srcA[h][c] + (long)kt * 128,
                       &lds[(buf * 2 + h) * 16384 + c * 8192 + t * 16]);
    };
    auto stB = [&](int kt, int h) {
        const int buf = kt & 1;
        #pragma unroll
        for (int c = 0; c < BNH; ++c)
            load_lds16(Bb + srcB[h][c] + (long)kt * 128,
                       &lds[65536 + (buf * 2 + h) * (BNH * 8192) + c * 8192 + t * 16]);
    };

    constexpr int MF = (BNH == 2) ? 8 : 4;
    f32x4 acc[MF][4] = {};
    bf16x8 a[4][2], b0[2][2], b1[2][2];
    const int nt = K >> 6;                    // K-tiles (even for all our shapes)

    if constexpr (BNH == 2) {
        // ---- prologue: tile 0 fully + B of tile 1 ----
        stB(0, 0); stB(0, 1); stA(0, 0); stA(0, 1); stB(1, 0); stB(1, 1);
        asm volatile("s_waitcnt vmcnt(4)" ::: "memory");
        __builtin_amdgcn_s_barrier();

        for (int u = 0; u < nt; u += 2) {
            const bool pf = (u + 2) < nt;
            // p1: (m0,n0) of tile u
            READA2(0, 0); READB2(0, 0, b0);
            stA(u + 1, 0);
            MFMA16(0, 0, b0)
            // p2: (m0,n1)
            READB2(0, 1, b1);
            stA(u + 1, 1);
            MFMA16(0, 2, b1)
            // p3: (m1,n1)
            READA2(0, 1);
            if (pf) stB(u + 2, 0);
            MFMA16(4, 2, b1)
            // p4: (m1,n0)  [checkpoint C1: tile u+1 landed]
            if (pf) { stB(u + 2, 1); asm volatile("s_waitcnt vmcnt(4)" ::: "memory"); }
            else    { asm volatile("s_waitcnt vmcnt(0)" ::: "memory"); }
            MFMA16(4, 0, b0)
            // p5: (m0,n0) of tile u+1
            READA2(1, 0); READB2(1, 0, b0);
            if (pf) stA(u + 2, 0);
            MFMA16(0, 0, b0)
            // p6: (m0,n1)
            READB2(1, 1, b1);
            if (pf) stA(u + 2, 1);
            MFMA16(0, 2, b1)
            // p7: (m1,n1)
            READA2(1, 1);
            if (pf) stB(u + 3, 0);
            MFMA16(4, 2, b1)
            // p8: (m1,n0)  [checkpoint C2: tile u+2 landed]
            if (pf) { stB(u + 3, 1); asm volatile("s_waitcnt vmcnt(4)" ::: "memory"); }
            else    { asm volatile("s_waitcnt vmcnt(0)" ::: "memory"); }
            MFMA16(4, 0, b0)
        }
    } else {
        // ---- prologue: tiles 0 and 1 ----
        stA(0, 0); stA(0, 1); stB(0, 0); stB(0, 1);
        stA(1, 0); stA(1, 1); stB(1, 0); stB(1, 1);
        asm volatile("s_waitcnt vmcnt(6)" ::: "memory");
        __builtin_amdgcn_s_barrier();

        for (int u = 0; u < nt; u += 2) {
            const bool pf = (u + 2) < nt;
            // p1: tile u, n-group 0
            READA1(0); READB1(0, 0, b0);
            if (pf) stA(u + 2, 0);
            MFMA16(0, 0, b0)
            // p2: tile u, n-group 1  [checkpoint: tile u+1 landed]
            READB1(0, 1, b1);
            if (pf) { stA(u + 2, 1); stB(u + 2, 0); stB(u + 2, 1);
                      asm volatile("s_waitcnt vmcnt(6)" ::: "memory"); }
            else    { asm volatile("s_waitcnt vmcnt(0)" ::: "memory"); }
            MFMA16(0, 2, b1)
            // p3: tile u+1, n-group 0
            READA1(1); READB1(1, 0, b0);
            if (pf) stA(u + 3, 0);
            MFMA16(0, 0, b0)
            // p4: tile u+1, n-group 1  [checkpoint: tile u+2 landed]
            READB1(1, 1, b1);
            if (pf) { stA(u + 3, 1); stB(u + 3, 0); stB(u + 3, 1);
                      asm volatile("s_waitcnt vmcnt(6)" ::: "memory"); }
            else    { asm volatile("s_waitcnt vmcnt(0)" ::: "memory"); }
            MFMA16(0, 2, b1)
        }
    }

    // ---- epilogue ----
    const int wrows = (BNH == 2) ? 128 : 64;
    #pragma unroll
    for (int mf = 0; mf < MF; ++mf)
      #pragma unroll
      for (int nf = 0; nf < 4; ++nf)
        #pragma unroll
        for (int r = 0; r < 4; ++r) {
            const int grow = bm * 256 + wr * wrows + mf * 16 + lk * 4 + r;
            const int gcol = bn * BN + wc * 64 + nf * 16 + lm;
            const float v = acc[mf][nf][r];
            if constexpr (EPI == 0) {
                ((short*)outp)[(long)grow * N + gcol] = to_bf16s(v);
            } else if constexpr (EPI == 2) {
                const long i = (long)grow * N + gcol;
                ((float*)outp)[i] = res[i] + v;
            } else if constexpr (EPI == 4) {
                const long i = (long)grow * N + gcol;
                const float g = bf16s_to_f(aux[i]);
                const float sws = g / (1.f + __expf(-g));
                ((short*)outp)[i] = to_bf16s(sws * v);
            } else {  // EPI 5: QKV split
                if (gcol < 2048)
                    ((short*)outp)[(long)grow * 2048 + gcol] = to_bf16s(v);
                else
                    outp2[(long)(gcol - 2048) * 8192 + grow] = to_bf16s(v);
            }
        }
}

// ---------------------------------------------------------------------------
// Windowed causal attention (WINDOW=64, D=1024).  32 queries / block,
// 96-key span.  Q,K bf16 rows of stride ldq; VT bf16 [1024][8192]; att bf16.
// ---------------------------------------------------------------------------
__global__ __launch_bounds__(128)
void attn_kernel(const short* __restrict__ Q, const short* __restrict__ Km,
                 int ldq, const short* __restrict__ VT, short* __restrict__ att) {
    const int T = 2048, D = 1024, Mtot = 8192;
    const int bid = blockIdx.x;
    const int b = bid >> 6;
    const int q0 = (bid & 63) << 5;
    const long qrow0 = (long)b * T + q0;
    const int t = threadIdx.x, lane = t & 63, w = t >> 6;

    __shared__ short Qs[32 * 32];
    __shared__ short Ks[96 * 32];
    __shared__ float S_lds[32][100];
    __shared__ short P_lds[32 * 96];
    __shared__ short VTs[128 * 96];

    f32x4 s[6] = {};
    const int trow = t >> 2, tk8 = (t & 3) * 8;
    for (int kt = 0; kt < 32; ++kt) {
        const int k0 = kt << 5;
        load_lds16(Q + (qrow0 + trow) * ldq + k0 + tk8, &Qs[t * 8]);
        #pragma unroll
        for (int s2 = 0; s2 < 3; ++s2) {
            const int krow = s2 * 32 + trow;
            int j = q0 - 64 + krow; if (j < 0) j = 0;
            load_lds16(Km + ((long)b * T + j) * ldq + k0 + tk8, &Ks[(s2 * 128 + t) * 8]);
        }
        __syncthreads();
        const int ko = (lane >> 4) * 8;
        const bf16x8 aq = *(const bf16x8*)&Qs[(w * 16 + (lane & 15)) * 32 + ko];
        #pragma unroll
        for (int n = 0; n < 6; ++n) {
            const bf16x8 bk = *(const bf16x8*)&Ks[(n * 16 + (lane & 15)) * 32 + ko];
            s[n] = __builtin_amdgcn_mfma_f32_16x16x32_bf16(aq, bk, s[n], 0, 0, 0);
        }
        __syncthreads();
    }
    #pragma unroll
    for (int n = 0; n < 6; ++n)
        #pragma unroll
        for (int r = 0; r < 4; ++r)
            S_lds[w * 16 + ((lane >> 4) << 2) + r][n * 16 + (lane & 15)] = s[n][r] * 0.03125f;
    __syncthreads();

    {
        const int row = t >> 2, c0 = (t & 3) * 24;
        float e[24];
        float mx = -1e30f;
        #pragma unroll
        for (int c = 0; c < 24; ++c) {
            const int kj = c0 + c;
            const bool valid = (kj > row) && (kj <= row + 64) && (q0 - 64 + kj >= 0);
            const float sv = valid ? S_lds[row][kj] : -1e30f;
            e[c] = sv;
            mx = fmaxf(mx, sv);
        }
        mx = fmaxf(mx, __shfl_xor(mx, 1));
        mx = fmaxf(mx, __shfl_xor(mx, 2));
        float sum = 0.f;
        #pragma unroll
        for (int c = 0; c < 24; ++c) {
            const float ev = (e[c] > -1e29f) ? __expf(e[c] - mx) : 0.f;
            e[c] = ev; sum += ev;
        }
        sum += __shfl_xor(sum, 1);
        sum += __shfl_xor(sum, 2);
        const float inv = 1.f / sum;
        #pragma unroll
        for (int c = 0; c < 24; ++c)
            P_lds[row * 96 + c0 + c] = to_bf16s(e[c] * inv);
    }
    __syncthreads();

    bf16x8 pa[3];
    {
        const int ko = (lane >> 4) * 8;
        #pragma unroll
        for (int kc = 0; kc < 3; ++kc)
            pa[kc] = *(const bf16x8*)&P_lds[(w * 16 + (lane & 15)) * 96 + kc * 32 + ko];
    }
    for (int dc = 0; dc < 8; ++dc) {
        #pragma unroll
        for (int s2 = 0; s2 < 12; ++s2) {
            const int idx = s2 * 128 + t;
            const int dr = idx / 12, c = idx - dr * 12;
            int j = q0 - 64 + c * 8; if (j < 0) j = 0;
            load_lds16(VT + (long)(dc * 128 + dr) * Mtot + b * T + j, &VTs[idx * 8]);
        }
        __syncthreads();
        f32x4 o[8] = {};
        const int ko = (lane >> 4) * 8;
        #pragma unroll
        for (int kc = 0; kc < 3; ++kc)
            #pragma unroll
            for (int n = 0; n < 8; ++n) {
                const bf16x8 vb = *(const bf16x8*)&VTs[(n * 16 + (lane & 15)) * 96 + kc * 32 + ko];
                o[n] = __builtin_amdgcn_mfma_f32_16x16x32_bf16(pa[kc], vb, o[n], 0, 0, 0);
            }
        __syncthreads();
        #pragma unroll
        for (int n = 0; n < 8; ++n)
            #pragma unroll
            for (int r = 0; r < 4; ++r) {
                const long grow = qrow0 + w * 16 + ((lane >> 4) << 2) + r;
                const int gcol = dc * 128 + n * 16 + (lane & 15);
                att[grow * D + gcol] = to_bf16s(o[n][r]);
            }
    }
}

// ---------------------------------------------------------------------------
extern "C" void kernel_launch(void* const* d_in, const int* in_sizes, int n_in,
                              void* d_out, int out_size, void* d_ws, size_t ws_size,
                              hipStream_t stream) {
    const float* x   = (const float*)d_in[0];
    const float* n1w = (const float*)d_in[1];
    const float* n2w = (const float*)d_in[2];
    const float* Wq  = (const float*)d_in[3];
    const float* Wk  = (const float*)d_in[4];
    const float* Wv  = (const float*)d_in[5];
    const float* Wo  = (const float*)d_in[6];
    const float* W1  = (const float*)d_in[7];
    const float* W2  = (const float*)d_in[8];
    const float* W3  = (const float*)d_in[9];

    const int M = 8192;           // B*T
    char* ws = (char*)d_ws;
    size_t off = 0;
    auto alloc = [&](size_t bytes) { void* p = ws + off; off += (bytes + 255) & ~(size_t)255; return p; };

    short* xn1 = (short*)alloc((size_t)M * 1024 * 2);   // reused as att
    short* qk  = (short*)alloc((size_t)M * 2048 * 2);   // q | k interleaved rows (ld=2048)
    short* vT  = (short*)alloc((size_t)M * 1024 * 2);   // V^T [1024][8192]
    float* x2  = (float*)alloc((size_t)M * 1024 * 4);
    short* WqT = (short*)alloc((size_t)1024 * 1024 * 2);   // WqT,WkT,WvT contiguous ->
    short* WkT = (short*)alloc((size_t)1024 * 1024 * 2);   //   [3072][1024] fused QKV weight
    short* WvT = (short*)alloc((size_t)1024 * 1024 * 2);
    short* WoT = (short*)alloc((size_t)1024 * 1024 * 2);
    short* W1T = (short*)alloc((size_t)2048 * 1024 * 2);
    short* W3T = (short*)alloc((size_t)2048 * 1024 * 2);
    short* W2T = (short*)alloc((size_t)1024 * 2048 * 2);
    short* att = xn1;                                   // xn1 dead after QKV
    short* xn2 = qk;                                    // q/k dead after attention
    short* g1  = qk + (size_t)M * 1024;                 // spans qk 2nd half + vT (33.5MB)

    transpose_all<<<10240, 256, 0, stream>>>(Wq, Wk, Wv, Wo, W1, W3, W2,
                                             WqT, WkT, WvT, WoT, W1T, W3T, W2T);

    // norm1 -> xn1 (bf16)
    rmsnorm_kernel<<<M, 256, 0, stream>>>(x, n1w, xn1);
    // fused QKV: [M,3072]; cols<2048 -> qk (ld 2048), cols>=2048 -> vT transposed
    gemm256<5, 1><<<768, 512, 0, stream>>>(xn1, WqT, nullptr, nullptr, qk, vT, M, 3072, 1024);
    // attention -> att (bf16)
    attn_kernel<<<256, 128, 0, stream>>>(qk, qk + 1024, 2048, vT, att);
    // x2 = x + att @ Wo   (fp32)
    gemm256<2, 1><<<256, 512, 0, stream>>>(att, WoT, nullptr, x, x2, nullptr, M, 1024, 1024);
    // norm2 -> xn2 (bf16)
    rmsnorm_kernel<<<M, 256, 0, stream>>>(x2, n2w, xn2);
    // g1 = xn2 @ W1   (bf16)
    gemm256<0, 2><<<256, 512, 0, stream>>>(xn2, W1T, nullptr, nullptr, g1, nullptr, M, 2048, 1024);
    // h = silu(g1) * (xn2 @ W3)   (bf16, in-place over g1)
    gemm256<4, 2><<<256, 512, 0, stream>>>(xn2, W3T, g1, nullptr, g1, nullptr, M, 2048, 1024);
    // out = x2 + h @ W2   (fp32)
    gemm256<2, 1><<<256, 512, 0, stream>>>(g1, W2T, nullptr, x2, (float*)d_out, nullptr, M, 1024, 2048);
}